// Round 5
// baseline (617.201 us; speedup 1.0000x reference)
//
#include <hip/hip_runtime.h>
#include <hip/hip_bf16.h>
#include <stdint.h>

// Problem constants (fixed by setup_inputs)
#define NB    8
#define LQ    2048
#define LKK   2048
#define EMBD  1024

typedef __bf16 bf16_t;
typedef __bf16 bf16x8 __attribute__((ext_vector_type(8)));
typedef __bf16 bf16x4 __attribute__((ext_vector_type(4)));
typedef float  f32x4  __attribute__((ext_vector_type(4)));

// RNE float->bf16, branch-free (inputs are finite)
__device__ __forceinline__ bf16_t f2bf(float x) {
  union { float f; uint32_t u; } v; v.f = x;
  uint32_t r = v.u + 0x7fffu + ((v.u >> 16) & 1u);
  uint16_t h = (uint16_t)(r >> 16);
  return __builtin_bit_cast(bf16_t, h);
}

__device__ __forceinline__ float wred_sum(float v) {
#pragma unroll
  for (int o = 32; o; o >>= 1) v += __shfl_xor(v, o);
  return v;
}
__device__ __forceinline__ float wred_max(float v) {
#pragma unroll
  for (int o = 32; o; o >>= 1) v = fmaxf(v, __shfl_xor(v, o));
  return v;
}

// ---------------------------------------------------------------------------
// Batched NT GEMM: C[z][M,N] = A[z][M,K] @ B[z][N,K]^T  (bf16 in, f32 acc)
// 256x256 tile, BK=32, 8 waves (512 thr) as 2M x 4N (each wave 128x64 out).
// FOUR LDS buffers (128 KiB), prefetch depth 3, COUNTED vmcnt (T4):
//   per K-tile:  waitcnt vmcnt(8) lgkmcnt(0); s_barrier; STAGE(t+3); COMPUTE(t)
//   vmcnt never drains to 0 in the main loop -> staged loads stay in flight
//   across barriers (the m97/2-phase structure's ~70% drain stall removed).
// Race audit: RAW tile t -> per-wave vmcnt(8) keeps only tiles t+1,t+2 in
//   flight, barrier collects all waves. WAR buf (t+3)&3 == (t-1)&3 -> every
//   wave's reads of it completed before its iteration-t barrier (lgkmcnt(0)
//   forced pre-barrier), stage is issued post-barrier. sched_barrier(0) pins
//   compiler motion (rule #18). LDS dest stays linear (rule #21).
// LDS layout K-slice-major [buf][slice4][row256][8 bf16]: linear in the
// global_load_lds slot order AND conflict-free on ds_read_b128.
// EPI: 0 = bf16 store with scale; 1 = bf16 plain; 2 = +bias ReLU bf16;
//      3 = +bias f32.
// ---------------------------------------------------------------------------
template<int EPI>
__global__ __launch_bounds__(512, 2)
void gemm_nt(const bf16_t* __restrict__ A, const bf16_t* __restrict__ B,
             float* __restrict__ Cf, bf16_t* __restrict__ Cb,
             const float* __restrict__ bias, float scale,
             int M, int N, int K, long sA, long sB, long sC)
{
  __shared__ __align__(16) bf16_t Al[4][4][256][8];   // 64 KiB
  __shared__ __align__(16) bf16_t Bl[4][4][256][8];   // 64 KiB

  const int tid  = threadIdx.x;
  const int lane = tid & 63;
  const int wave = tid >> 6;          // 0..7

  // XCD-aware bijective swizzle over the flattened 3D grid (total % 8 == 0)
  const int nbx = gridDim.x, nby = gridDim.y;
  const int total = nbx * nby * gridDim.z;
  int f = ((int)blockIdx.z * nby + (int)blockIdx.y) * nbx + (int)blockIdx.x;
  if ((total & 7) == 0) { const int cpx = total >> 3; f = (f & 7) * cpx + (f >> 3); }
  const int bxi = f % nbx;
  const int byi = (f / nbx) % nby;
  const int bz  = f / (nbx * nby);

  const bf16_t* Ab = A + (long)bz * sA;
  const bf16_t* Bb = B + (long)bz * sB;

  const int bm = bxi * 256;
  const int bn = byi * 256;
  const int wm = (wave >> 2) * 128;   // 2 M-halves
  const int wn = (wave & 3) * 64;     // 4 N-quarters

  f32x4 acc[8][4] = {};

  // staging: thread t, issue i -> LDS slot s = tid + i*512 (16B each);
  // slot -> slice = s>>8 (= (tid>>8)+2i), row = s&255 (= tid&255).
  const int srow = tid & 255;
  const int sslc = tid >> 8;          // 0 or 1

  // fragment read coords: lane l -> row (l&15), k-slice (l>>4)
  const int fr = lane & 15;
  const int fs = lane >> 4;

  auto STAGE = [&](int bufi, int kt) {
    char* abase = (char*)&Al[bufi][0][0][0];
    char* bbase = (char*)&Bl[bufi][0][0][0];
#pragma unroll
    for (int i = 0; i < 2; i++) {
      const int slc = sslc + 2 * i;
      __builtin_amdgcn_global_load_lds(
        (const __attribute__((address_space(1))) void*)(Ab + (long)(bm + srow) * K + kt + slc * 8),
        (__attribute__((address_space(3))) void*)(abase + (tid + i * 512) * 16),
        16, 0, 0);
      __builtin_amdgcn_global_load_lds(
        (const __attribute__((address_space(1))) void*)(Bb + (long)(bn + srow) * K + kt + slc * 8),
        (__attribute__((address_space(3))) void*)(bbase + (tid + i * 512) * 16),
        16, 0, 0);
    }
  };

  auto COMPUTE = [&](int bufi) {
    bf16x8 af[8], bfg[4];
#pragma unroll
    for (int m = 0; m < 8; m++)
      af[m] = *(const bf16x8*)&Al[bufi][fs][wm + m * 16 + fr][0];
#pragma unroll
    for (int n = 0; n < 4; n++)
      bfg[n] = *(const bf16x8*)&Bl[bufi][fs][wn + n * 16 + fr][0];
    __builtin_amdgcn_s_setprio(1);
#pragma unroll
    for (int m = 0; m < 8; m++)
#pragma unroll
      for (int n = 0; n < 4; n++)
        acc[m][n] = __builtin_amdgcn_mfma_f32_16x16x32_bf16(af[m], bfg[n], acc[m][n], 0, 0, 0);
    __builtin_amdgcn_s_setprio(0);
  };

  const int nt = K >> 5;              // K-tiles of 32 (K >= 96 always here)
  // prologue: stage tiles 0,1,2 -> 12 loads in flight
  STAGE(0, 0); STAGE(1, 32); STAGE(2, 64);

  for (int t = 0; t < nt; ++t) {
    const int rem = nt - 1 - t;
    __builtin_amdgcn_sched_barrier(0);
    if (rem >= 2)      asm volatile("s_waitcnt vmcnt(8) lgkmcnt(0)" ::: "memory");
    else if (rem == 1) asm volatile("s_waitcnt vmcnt(4) lgkmcnt(0)" ::: "memory");
    else               asm volatile("s_waitcnt vmcnt(0) lgkmcnt(0)" ::: "memory");
    __builtin_amdgcn_s_barrier();
    __builtin_amdgcn_sched_barrier(0);
    if (t + 3 < nt) STAGE((t + 3) & 3, (t + 3) << 5);
    COMPUTE(t & 3);
  }

  // C/D layout (m89-verified): col = lane&15, row = (lane>>4)*4 + j
  const int r0 = bm + wm + ((lane >> 4) << 2);
  const int c0 = bn + wn + fr;
  const long cb = (long)bz * sC;
#pragma unroll
  for (int n = 0; n < 4; n++) {
    const int col = c0 + n * 16;
    float bv = 0.0f;
    if constexpr (EPI >= 2) bv = bias[col];
#pragma unroll
    for (int m = 0; m < 8; m++) {
#pragma unroll
      for (int j = 0; j < 4; j++) {
        const int row = r0 + m * 16 + j;
        const long idx = cb + (long)row * N + col;
        float v = acc[m][n][j];
        if constexpr (EPI == 0)      { Cb[idx] = f2bf(v * scale); }
        else if constexpr (EPI == 1) { Cb[idx] = f2bf(v); }
        else if constexpr (EPI == 2) { v += bv; Cb[idx] = f2bf(fmaxf(v, 0.0f)); }
        else                         { v += bv; Cf[idx] = v; }
      }
    }
  }
}

// ---------------------------------------------------------------------------
// Row softmax over S [(nb)*LQ][LKK] bf16 (already scaled) -> P bf16, in-place
// capable (P may == S). km/qm pointers pre-offset to the batch range.
// ---------------------------------------------------------------------------
__global__ __launch_bounds__(256)
void softmax_kernel(const bf16_t* __restrict__ S, bf16_t* __restrict__ P,
                    const float* __restrict__ km, const float* __restrict__ qm)
{
  __shared__ float red[8];
  const int r = blockIdx.x;
  const int b = r >> 11;              // local batch index (r / LQ)
  const int t = threadIdx.x;
  const bf16_t* row = S + (long)r * LKK;

  const bf16x8 sv = *(const bf16x8*)(row + t * 8);
  const float4 k0 = ((const float4*)(km + (long)b * LKK))[2 * t];
  const float4 k1 = ((const float4*)(km + (long)b * LKK))[2 * t + 1];
  const float kmv[8] = {k0.x, k0.y, k0.z, k0.w, k1.x, k1.y, k1.z, k1.w};

  float v[8];
  float mx = -3.4e38f;
#pragma unroll
  for (int i = 0; i < 8; i++) {
    float s = (float)sv[i];
    s = (kmv[i] == 0.0f) ? -4294967295.0f : s;   // NEG_INF
    v[i] = s;
    mx = fmaxf(mx, s);
  }
  mx = wred_max(mx);
  if ((t & 63) == 0) red[t >> 6] = mx;
  __syncthreads();
  mx = fmaxf(fmaxf(red[0], red[1]), fmaxf(red[2], red[3]));

  float sum = 0.0f;
#pragma unroll
  for (int i = 0; i < 8; i++) {
    const float e = __expf(v[i] - mx);
    v[i] = e;
    sum += e;
  }
  sum = wred_sum(sum);
  if ((t & 63) == 0) red[4 + (t >> 6)] = sum;
  __syncthreads();
  sum = red[4] + red[5] + red[6] + red[7];

  const float rs = qm[r] / sum;
  bf16x8 o;
#pragma unroll
  for (int i = 0; i < 8; i++) o[i] = f2bf(v[i] * rs);
  *(bf16x8*)(P + (long)r * LKK + t * 8) = o;
}

// ---------------------------------------------------------------------------
// Fused residual + LayerNorm: Y = LN(X + R)*w + b  (rows of EMBD)
// MODE bit0: X bf16 (else f32); bit1: R bf16; bit2: Y bf16 (else f32).
// In-place (Y==X) safe: per-thread same-address read-then-write.
// ---------------------------------------------------------------------------
template<int MODE>
__global__ __launch_bounds__(256)
void ln_kernel(const void* __restrict__ Xv, const void* __restrict__ Rv,
               const float* __restrict__ w, const float* __restrict__ bp,
               void* __restrict__ Yv)
{
  __shared__ float red[8];
  const long r = blockIdx.x;
  const int t = threadIdx.x;

  float x0, x1, x2, x3;
  if constexpr (MODE & 1) {
    const bf16x4 xv = ((const bf16x4*)((const bf16_t*)Xv + r * EMBD))[t];
    x0 = (float)xv[0]; x1 = (float)xv[1]; x2 = (float)xv[2]; x3 = (float)xv[3];
  } else {
    const float4 xv = ((const float4*)((const float*)Xv + r * EMBD))[t];
    x0 = xv.x; x1 = xv.y; x2 = xv.z; x3 = xv.w;
  }
  float r0, r1, r2, r3;
  if constexpr (MODE & 2) {
    const bf16x4 rv = ((const bf16x4*)((const bf16_t*)Rv + r * EMBD))[t];
    r0 = (float)rv[0]; r1 = (float)rv[1]; r2 = (float)rv[2]; r3 = (float)rv[3];
  } else {
    const float4 rv = ((const float4*)((const float*)Rv + r * EMBD))[t];
    r0 = rv.x; r1 = rv.y; r2 = rv.z; r3 = rv.w;
  }
  const float s0 = x0 + r0, s1 = x1 + r1, s2 = x2 + r2, s3 = x3 + r3;

  float sum = wred_sum(s0 + s1 + s2 + s3);
  if ((t & 63) == 0) red[t >> 6] = sum;
  __syncthreads();
  const float mu = (red[0] + red[1] + red[2] + red[3]) * (1.0f / EMBD);

  const float d0 = s0 - mu, d1 = s1 - mu, d2 = s2 - mu, d3 = s3 - mu;
  float sq = wred_sum(d0 * d0 + d1 * d1 + d2 * d2 + d3 * d3);
  if ((t & 63) == 0) red[4 + (t >> 6)] = sq;
  __syncthreads();
  const float var = (red[4] + red[5] + red[6] + red[7]) * (1.0f / EMBD);
  const float rstd = rsqrtf(var + 1e-5f);

  const float4 wv = ((const float4*)w)[t];
  const float4 bv = ((const float4*)bp)[t];
  const float y0 = d0 * rstd * wv.x + bv.x;
  const float y1 = d1 * rstd * wv.y + bv.y;
  const float y2 = d2 * rstd * wv.z + bv.z;
  const float y3 = d3 * rstd * wv.w + bv.w;

  if constexpr (MODE & 4) {
    bf16x4 o; o[0] = f2bf(y0); o[1] = f2bf(y1); o[2] = f2bf(y2); o[3] = f2bf(y3);
    ((bf16x4*)((bf16_t*)Yv + r * EMBD))[t] = o;
  } else {
    ((float4*)((float*)Yv + r * EMBD))[t] = make_float4(y0, y1, y2, y3);
  }
}

// flat f32 -> bf16 (vectorized, grid-stride)
__global__ void cvt_kernel(const float* __restrict__ in, bf16_t* __restrict__ out, long n4)
{
  long i = (long)blockIdx.x * 256 + threadIdx.x;
  const long stride = (long)gridDim.x * 256;
  for (; i < n4; i += stride) {
    const float4 v = ((const float4*)in)[i];
    bf16x4 o; o[0] = f2bf(v.x); o[1] = f2bf(v.y); o[2] = f2bf(v.z); o[3] = f2bf(v.w);
    ((bf16x4*)out)[i] = o;
  }
}

// batched [z][rows][cols] f32 -> [z][cols][rows] bf16 (tiled transpose via LDS)
__global__ __launch_bounds__(256)
void transpose_cvt(const float* __restrict__ in, bf16_t* __restrict__ out,
                   int rows, int cols)
{
  __shared__ bf16_t tile[32][33];
  const long zb = (long)blockIdx.z * rows * cols;
  const int cb = blockIdx.x * 32;      // col coord
  const int rb = blockIdx.y * 32;      // row coord
  const int tx = threadIdx.x & 31;
  const int ty = threadIdx.x >> 5;     // 0..7
#pragma unroll
  for (int i = 0; i < 4; i++) {
    const int rr = ty + i * 8;
    tile[rr][tx] = f2bf(in[zb + (long)(rb + rr) * cols + cb + tx]);
  }
  __syncthreads();
#pragma unroll
  for (int i = 0; i < 4; i++) {
    const int cc = ty + i * 8;
    out[zb + (long)(cb + cc) * rows + rb + tx] = tile[tx][cc];
  }
}

// ---------------------------------------------------------------------------
extern "C" void kernel_launch(void* const* d_in, const int* in_sizes, int n_in,
                              void* d_out, int out_size, void* d_ws, size_t ws_size,
                              hipStream_t stream)
{
  const float* q    = (const float*)d_in[0];
  const float* k    = (const float*)d_in[1];
  const float* qm   = (const float*)d_in[2];
  const float* km   = (const float*)d_in[3];
  const float* lnw  = (const float*)d_in[4];
  const float* lnb  = (const float*)d_in[5];
  const float* ln2w = (const float*)d_in[6];
  const float* ln2b = (const float*)d_in[7];
  const float* W1   = (const float*)d_in[8];
  const float* b1   = (const float*)d_in[9];
  const float* W2   = (const float*)d_in[10];
  const float* b2   = (const float*)d_in[11];

  char* ws = (char*)d_ws;
  char* ob = (char*)d_out;
  const float scale = 0.03125f;             // 1/(sqrt(1024)+1e-8)
  const long MB = 1L << 20;
  const long QE = (long)LQ * EMBD;          // 2M elems per batch (Q-shaped)
  const long SS = (long)LQ * LKK;           // 4M elems per batch (S-shaped)

  if (ws_size >= 100 * MB) {
    // ================= Tier A: fully batched (z=8) =================
    // ws:  [0,32) Qb -> attn   [32,64) Kb -> h   [64,96) Kt   [96,100) W1b,W2b
    // out: [0,64) S/P bf16 (in-place softmax) -> y f32
    bf16_t* Qb   = (bf16_t*)ws;
    bf16_t* attn = (bf16_t*)ws;                  // overlays Qb (dead after QK)
    bf16_t* Kb   = (bf16_t*)(ws + 32 * MB);
    bf16_t* h    = (bf16_t*)(ws + 32 * MB);      // overlays Kb (dead after QK)
    bf16_t* Kt   = (bf16_t*)(ws + 64 * MB);
    bf16_t* W1b  = (bf16_t*)(ws + 96 * MB);
    bf16_t* W2b  = (bf16_t*)(ws + 98 * MB);
    bf16_t* Sb   = (bf16_t*)ob;                  // 64 MiB, whole d_out
    float*  y    = (float*)ob;

    cvt_kernel<<<1024, 256, 0, stream>>>(W1, W1b, (long)EMBD * EMBD / 4);
    cvt_kernel<<<1024, 256, 0, stream>>>(W2, W2b, (long)EMBD * EMBD / 4);
    cvt_kernel<<<4096, 256, 0, stream>>>(q, Qb, (long)NB * QE / 4);
    cvt_kernel<<<4096, 256, 0, stream>>>(k, Kb, (long)NB * QE / 4);
    transpose_cvt<<<dim3(EMBD / 32, LKK / 32, NB), 256, 0, stream>>>(k, Kt, LKK, EMBD);

    // S = (Q K^T)/32
    gemm_nt<0><<<dim3(LQ / 256, LKK / 256, NB), 512, 0, stream>>>(
        Qb, Kb, nullptr, Sb, nullptr, scale, LQ, LKK, EMBD, QE, QE, SS);
    // P = qmask * softmax(mask(S))   (in-place)
    softmax_kernel<<<NB * LQ, 256, 0, stream>>>(Sb, Sb, km, qm);
    // attn = P @ K
    gemm_nt<1><<<dim3(LQ / 256, EMBD / 256, NB), 512, 0, stream>>>(
        Sb, Kt, nullptr, attn, nullptr, 0.0f, LQ, EMBD, LKK, SS, (long)EMBD * LKK, QE);
    // x = LN(attn + q) in-place
    ln_kernel<5><<<NB * LQ, 256, 0, stream>>>(attn, q, lnw, lnb, attn);
    // FFN single-shot over 16384 rows
    gemm_nt<2><<<dim3(NB * LQ / 256, EMBD / 256, 1), 512, 0, stream>>>(
        attn, W1b, nullptr, h, b1, 0.0f, NB * LQ, EMBD, EMBD, 0, 0, 0);
    gemm_nt<3><<<dim3(NB * LQ / 256, EMBD / 256, 1), 512, 0, stream>>>(
        h, W2b, y, nullptr, b2, 0.0f, NB * LQ, EMBD, EMBD, 0, 0, 0);
    // out = LN(y + x) in-place
    ln_kernel<2><<<NB * LQ, 256, 0, stream>>>(y, attn, ln2w, ln2b, y);

  } else if (ws_size >= 52 * MB) {
    // ================= Tier B: two half-batches (z=4) =================
    bf16_t* attn = (bf16_t*)ws;
    bf16_t* W1b  = (bf16_t*)(ws + 32 * MB);
    bf16_t* W2b  = (bf16_t*)(ws + 34 * MB);
    bf16_t* Kth  = (bf16_t*)(ws + 36 * MB);
    bf16_t* h    = (bf16_t*)(ws + 36 * MB);      // overlays Kth (dead after PV)
    bf16_t* Sb   = (bf16_t*)ob;
    bf16_t* Qbh  = (bf16_t*)(ob + 32 * MB);
    bf16_t* Kbh  = (bf16_t*)(ob + 48 * MB);
    float*  y    = (float*)ob;

    cvt_kernel<<<1024, 256, 0, stream>>>(W1, W1b, (long)EMBD * EMBD / 4);
    cvt_kernel<<<1024, 256, 0, stream>>>(W2, W2b, (long)EMBD * EMBD / 4);

    for (int it = 0; it < 2; it++) {
      const int bo = it * 4;
      const float* qh = q + bo * QE;
      const float* kh = k + bo * QE;
      cvt_kernel<<<2048, 256, 0, stream>>>(qh, Qbh, 4 * QE / 4);
      cvt_kernel<<<2048, 256, 0, stream>>>(kh, Kbh, 4 * QE / 4);
      transpose_cvt<<<dim3(EMBD / 32, LKK / 32, 4), 256, 0, stream>>>(kh, Kth, LKK, EMBD);

      gemm_nt<0><<<dim3(LQ / 256, LKK / 256, 4), 512, 0, stream>>>(
          Qbh, Kbh, nullptr, Sb, nullptr, scale, LQ, LKK, EMBD, QE, QE, SS);
      softmax_kernel<<<4 * LQ, 256, 0, stream>>>(Sb, Sb, km + bo * LKK, qm + bo * LQ);
      gemm_nt<1><<<dim3(LQ / 256, EMBD / 256, 4), 512, 0, stream>>>(
          Sb, Kth, nullptr, attn + bo * QE, nullptr, 0.0f, LQ, EMBD, LKK,
          SS, (long)EMBD * LKK, QE);
    }
    ln_kernel<5><<<NB * LQ, 256, 0, stream>>>(attn, q, lnw, lnb, attn);
    for (int c = 0; c < 2; c++) {
      bf16_t* xc = attn + (long)c * 8192 * EMBD;
      float*  yc = y + (long)c * 8192 * EMBD;
      gemm_nt<2><<<dim3(8192 / 256, EMBD / 256, 1), 512, 0, stream>>>(
          xc, W1b, nullptr, h, b1, 0.0f, 8192, EMBD, EMBD, 0, 0, 0);
      gemm_nt<3><<<dim3(8192 / 256, EMBD / 256, 1), 512, 0, stream>>>(
          h, W2b, yc, nullptr, b2, 0.0f, 8192, EMBD, EMBD, 0, 0, 0);
    }
    ln_kernel<2><<<NB * LQ, 256, 0, stream>>>(y, attn, ln2w, ln2b, y);

  } else {
    // ================= Tier C: per-batch 44 MiB fallback =================
    if (ws_size < 44 * MB) return;
    bf16_t* attn = (bf16_t*)ws;
    bf16_t* W1b  = (bf16_t*)(ws + 32 * MB);
    bf16_t* W2b  = (bf16_t*)(ws + 34 * MB);
    bf16_t* h    = (bf16_t*)(ws + 36 * MB);
    bf16_t* Sb   = (bf16_t*)(ob);
    bf16_t* Pb   = (bf16_t*)(ob + 8 * MB);
    bf16_t* Qbb  = (bf16_t*)(ob + 16 * MB);
    bf16_t* Kbb  = (bf16_t*)(ob + 20 * MB);
    bf16_t* Ktb  = (bf16_t*)(ob + 24 * MB);

    cvt_kernel<<<1024, 256, 0, stream>>>(W1, W1b, (long)EMBD * EMBD / 4);
    cvt_kernel<<<1024, 256, 0, stream>>>(W2, W2b, (long)EMBD * EMBD / 4);

    for (int b = 0; b < NB; b++) {
      const float* qb = q + b * QE;
      const float* kb = k + b * QE;
      cvt_kernel<<<2048, 256, 0, stream>>>(qb, Qbb, QE / 4);
      cvt_kernel<<<2048, 256, 0, stream>>>(kb, Kbb, QE / 4);
      transpose_cvt<<<dim3(EMBD / 32, LKK / 32, 1), 256, 0, stream>>>(kb, Ktb, LKK, EMBD);

      gemm_nt<0><<<dim3(LQ / 256, LKK / 256, 1), 512, 0, stream>>>(
          Qbb, Kbb, nullptr, Sb, nullptr, scale, LQ, LKK, EMBD, 0, 0, 0);
      softmax_kernel<<<LQ, 256, 0, stream>>>(Sb, Pb, km + (long)b * LKK, qm + (long)b * LQ);
      gemm_nt<1><<<dim3(LQ / 256, EMBD / 256, 1), 512, 0, stream>>>(
          Pb, Ktb, nullptr, attn + b * QE, nullptr, 0.0f, LQ, EMBD, LKK, 0, 0, 0);
    }
    ln_kernel<5><<<NB * LQ, 256, 0, stream>>>(attn, q, lnw, lnb, attn);
    for (int c = 0; c < 4; c++) {
      bf16_t* xc = attn + (long)c * 4096 * EMBD;
      float*  yc = (float*)d_out + (long)c * 4096 * EMBD;
      gemm_nt<2><<<dim3(4096 / 256, EMBD / 256, 1), 512, 0, stream>>>(
          xc, W1b, nullptr, h, b1, 0.0f, 4096, EMBD, EMBD, 0, 0, 0);
      gemm_nt<3><<<dim3(4096 / 256, EMBD / 256, 1), 512, 0, stream>>>(
          h, W2b, yc, nullptr, b2, 0.0f, 4096, EMBD, EMBD, 0, 0, 0);
      ln_kernel<2><<<4096, 256, 0, stream>>>(yc, xc, ln2w, ln2b, yc);
    }
  }
}

// Round 6
// 591.782 us; speedup vs baseline: 1.0430x; 1.0430x over previous
//
#include <hip/hip_runtime.h>
#include <hip/hip_bf16.h>
#include <stdint.h>

// Problem constants (fixed by setup_inputs)
#define NB    8
#define LQ    2048
#define LKK   2048
#define EMBD  1024

typedef __bf16 bf16_t;
typedef __bf16 bf16x8 __attribute__((ext_vector_type(8)));
typedef __bf16 bf16x4 __attribute__((ext_vector_type(4)));
typedef float  f32x4  __attribute__((ext_vector_type(4)));

// RNE float->bf16, branch-free (inputs are finite)
__device__ __forceinline__ bf16_t f2bf(float x) {
  union { float f; uint32_t u; } v; v.f = x;
  uint32_t r = v.u + 0x7fffu + ((v.u >> 16) & 1u);
  uint16_t h = (uint16_t)(r >> 16);
  return __builtin_bit_cast(bf16_t, h);
}

__device__ __forceinline__ float wred_sum(float v) {
#pragma unroll
  for (int o = 32; o; o >>= 1) v += __shfl_xor(v, o);
  return v;
}
__device__ __forceinline__ float wred_max(float v) {
#pragma unroll
  for (int o = 32; o; o >>= 1) v = fmaxf(v, __shfl_xor(v, o));
  return v;
}

// ---------------------------------------------------------------------------
// Batched NT GEMM: C[z][M,N] = A[z][M,K] @ B[z][N,K]^T  (bf16 in, f32 acc)
// 256x256 tile, BK=64, 8 waves (512 thr) as 2M x 4N (each wave 128x64 out).
// 8-phase-style schedule (T3+T4, m201 granularity): double-buffered LDS
// (128 KiB), 4 phases per K-tile, 16 MFMA per phase:
//   phase = { ds_read frags; [stage 4 gload_lds @ p0,p2]; s_barrier;
//             lgkmcnt(0)+sched_barrier; setprio(1); 16 MFMA; setprio(0);
//             [vmcnt(4) @ p1,p3 ends -- COUNTED, never 0 in steady state];
//             s_barrier }
// Race audit: phase-p ds_reads touch data staged >=3 phases earlier; the
// vmcnt(4) at p1/p3 retires exactly the stage-group two slots back (in-flight
// = 8 there). Tail tile (no prefetch) uses vmcnt(0) once. WAR: stage at
// t.p0/p2 overwrites t-1's half whose reads completed >=2 barriers earlier
// (per-wave lgkmcnt(0) pre-MFMA + end barrier). LDS layout K-slice-major
// [buf][slice8][row256][8 bf16]: linear in gload_lds slot order (rule #21)
// AND bank-conflict-free on ds_read_b128 (measured 0 conflicts).
// EPI: 0 = bf16 store with scale; 1 = bf16 plain; 2 = +bias ReLU bf16;
//      3 = +bias f32.
// ---------------------------------------------------------------------------
template<int EPI>
__global__ __launch_bounds__(512, 1)
void gemm_nt(const bf16_t* __restrict__ A, const bf16_t* __restrict__ B,
             float* __restrict__ Cf, bf16_t* __restrict__ Cb,
             const float* __restrict__ bias, float scale,
             int M, int N, int K, long sA, long sB, long sC)
{
  __shared__ __align__(16) bf16_t Al[2][8][256][8];   // 64 KiB
  __shared__ __align__(16) bf16_t Bl[2][8][256][8];   // 64 KiB

  const int tid  = threadIdx.x;
  const int lane = tid & 63;
  const int wave = tid >> 6;          // 0..7

  // XCD-aware bijective swizzle over the flattened 3D grid (total % 8 == 0)
  const int nbx = gridDim.x, nby = gridDim.y;
  const int total = nbx * nby * gridDim.z;
  int f = ((int)blockIdx.z * nby + (int)blockIdx.y) * nbx + (int)blockIdx.x;
  if ((total & 7) == 0) { const int cpx = total >> 3; f = (f & 7) * cpx + (f >> 3); }
  const int bxi = f % nbx;
  const int byi = (f / nbx) % nby;
  const int bz  = f / (nbx * nby);

  const bf16_t* Ab = A + (long)bz * sA;
  const bf16_t* Bb = B + (long)bz * sB;

  const int bm = bxi * 256;
  const int bn = byi * 256;
  const int wm = (wave >> 2) * 128;   // 2 M-halves
  const int wn = (wave & 3) * 64;     // 4 N-quarters

  f32x4 acc[8][4] = {};

  // fragment read coords: lane l -> row (l&15), k-slice (l>>4)
  const int fr = lane & 15;
  const int fs = lane >> 4;

  // stage one K-half (4 slices) of A AND B for tile at k-offset kt:
  // thread t, issue i -> slot = t + i*512 in [0,1024); slice = slot>>8,
  // row = slot&255; LDS dest linear = halfbase + slot*16.
  auto STAGE_HALF = [&](int b, int kt, int kh) {
    char* ab = (char*)&Al[b][0][0][0] + kh * 16384;
    char* bb = (char*)&Bl[b][0][0][0] + kh * 16384;
    const int kofs = kt + kh * 32;
#pragma unroll
    for (int i = 0; i < 2; i++) {
      const int slot = tid + i * 512;
      const int slc  = slot >> 8;
      const int row  = slot & 255;
      __builtin_amdgcn_global_load_lds(
        (const __attribute__((address_space(1))) void*)(Ab + (long)(bm + row) * K + kofs + slc * 8),
        (__attribute__((address_space(3))) void*)(ab + slot * 16), 16, 0, 0);
      __builtin_amdgcn_global_load_lds(
        (const __attribute__((address_space(1))) void*)(Bb + (long)(bn + row) * K + kofs + slc * 8),
        (__attribute__((address_space(3))) void*)(bb + slot * 16), 16, 0, 0);
    }
  };

  auto MFMA16 = [&](bf16x8* af, bf16x8 bx, bf16x8 by, int n0, int n1) {
    __builtin_amdgcn_s_setprio(1);
#pragma unroll
    for (int m = 0; m < 8; m++)
      acc[m][n0] = __builtin_amdgcn_mfma_f32_16x16x32_bf16(af[m], bx, acc[m][n0], 0, 0, 0);
#pragma unroll
    for (int m = 0; m < 8; m++)
      acc[m][n1] = __builtin_amdgcn_mfma_f32_16x16x32_bf16(af[m], by, acc[m][n1], 0, 0, 0);
    __builtin_amdgcn_s_setprio(0);
  };

  const int nt = K >> 6;              // K-tiles of 64 (nt >= 16 here)

  // prologue: stage tile 0 fully; wait half0 (4 newest = half1 may fly)
  STAGE_HALF(0, 0, 0);
  STAGE_HALF(0, 0, 1);
  asm volatile("s_waitcnt vmcnt(4)" ::: "memory");
  __builtin_amdgcn_s_barrier();

  for (int t = 0; t < nt; ++t) {
    const int cur = t & 1, nxt = cur ^ 1;
    const bool pf = (t + 1 < nt);
    const int ktn = (t + 1) << 6;
    bf16x8 af[8], b0, b1;

    // ---- phase 0: kk=0, n{0,1} ----
#pragma unroll
    for (int m = 0; m < 8; m++) af[m] = *(const bf16x8*)&Al[cur][fs][wm + m * 16 + fr][0];
    b0 = *(const bf16x8*)&Bl[cur][fs][wn + fr][0];
    b1 = *(const bf16x8*)&Bl[cur][fs][wn + 16 + fr][0];
    if (pf) STAGE_HALF(nxt, ktn, 0);
    __builtin_amdgcn_s_barrier();
    asm volatile("s_waitcnt lgkmcnt(0)" ::: "memory");
    __builtin_amdgcn_sched_barrier(0);
    MFMA16(af, b0, b1, 0, 1);
    __builtin_amdgcn_s_barrier();

    // ---- phase 1: kk=0, n{2,3} ----
    b0 = *(const bf16x8*)&Bl[cur][fs][wn + 32 + fr][0];
    b1 = *(const bf16x8*)&Bl[cur][fs][wn + 48 + fr][0];
    __builtin_amdgcn_s_barrier();
    asm volatile("s_waitcnt lgkmcnt(0)" ::: "memory");
    __builtin_amdgcn_sched_barrier(0);
    MFMA16(af, b0, b1, 2, 3);
    if (pf) asm volatile("s_waitcnt vmcnt(4)" ::: "memory");   // t.p0 group landed
    else    asm volatile("s_waitcnt vmcnt(0)" ::: "memory");   // tail: drain half1
    __builtin_amdgcn_s_barrier();

    // ---- phase 2: kk=1, n{0,1} ----
#pragma unroll
    for (int m = 0; m < 8; m++) af[m] = *(const bf16x8*)&Al[cur][4 + fs][wm + m * 16 + fr][0];
    b0 = *(const bf16x8*)&Bl[cur][4 + fs][wn + fr][0];
    b1 = *(const bf16x8*)&Bl[cur][4 + fs][wn + 16 + fr][0];
    if (pf) STAGE_HALF(nxt, ktn, 1);
    __builtin_amdgcn_s_barrier();
    asm volatile("s_waitcnt lgkmcnt(0)" ::: "memory");
    __builtin_amdgcn_sched_barrier(0);
    MFMA16(af, b0, b1, 0, 1);
    __builtin_amdgcn_s_barrier();

    // ---- phase 3: kk=1, n{2,3} ----
    b0 = *(const bf16x8*)&Bl[cur][4 + fs][wn + 32 + fr][0];
    b1 = *(const bf16x8*)&Bl[cur][4 + fs][wn + 48 + fr][0];
    __builtin_amdgcn_s_barrier();
    asm volatile("s_waitcnt lgkmcnt(0)" ::: "memory");
    __builtin_amdgcn_sched_barrier(0);
    MFMA16(af, b0, b1, 2, 3);
    if (pf) asm volatile("s_waitcnt vmcnt(4)" ::: "memory");   // t.p2 group landed
    __builtin_amdgcn_s_barrier();
  }

  // C/D layout (m89-verified): col = lane&15, row = (lane>>4)*4 + j
  const int r0 = bm + wm + ((lane >> 4) << 2);
  const int c0 = bn + wn + fr;
  const long cb = (long)bz * sC;
#pragma unroll
  for (int n = 0; n < 4; n++) {
    const int col = c0 + n * 16;
    float bv = 0.0f;
    if constexpr (EPI >= 2) bv = bias[col];
#pragma unroll
    for (int m = 0; m < 8; m++) {
#pragma unroll
      for (int j = 0; j < 4; j++) {
        const int row = r0 + m * 16 + j;
        const long idx = cb + (long)row * N + col;
        float v = acc[m][n][j];
        if constexpr (EPI == 0)      { Cb[idx] = f2bf(v * scale); }
        else if constexpr (EPI == 1) { Cb[idx] = f2bf(v); }
        else if constexpr (EPI == 2) { v += bv; Cb[idx] = f2bf(fmaxf(v, 0.0f)); }
        else                         { v += bv; Cf[idx] = v; }
      }
    }
  }
}

// ---------------------------------------------------------------------------
// Row softmax over S [(nb)*LQ][LKK] bf16 (already scaled) -> P bf16, in-place
// capable (P may == S). km/qm pointers pre-offset to the batch range.
// ---------------------------------------------------------------------------
__global__ __launch_bounds__(256)
void softmax_kernel(const bf16_t* __restrict__ S, bf16_t* __restrict__ P,
                    const float* __restrict__ km, const float* __restrict__ qm)
{
  __shared__ float red[8];
  const int r = blockIdx.x;
  const int b = r >> 11;              // local batch index (r / LQ)
  const int t = threadIdx.x;
  const bf16_t* row = S + (long)r * LKK;

  const bf16x8 sv = *(const bf16x8*)(row + t * 8);
  const float4 k0 = ((const float4*)(km + (long)b * LKK))[2 * t];
  const float4 k1 = ((const float4*)(km + (long)b * LKK))[2 * t + 1];
  const float kmv[8] = {k0.x, k0.y, k0.z, k0.w, k1.x, k1.y, k1.z, k1.w};

  float v[8];
  float mx = -3.4e38f;
#pragma unroll
  for (int i = 0; i < 8; i++) {
    float s = (float)sv[i];
    s = (kmv[i] == 0.0f) ? -4294967295.0f : s;   // NEG_INF
    v[i] = s;
    mx = fmaxf(mx, s);
  }
  mx = wred_max(mx);
  if ((t & 63) == 0) red[t >> 6] = mx;
  __syncthreads();
  mx = fmaxf(fmaxf(red[0], red[1]), fmaxf(red[2], red[3]));

  float sum = 0.0f;
#pragma unroll
  for (int i = 0; i < 8; i++) {
    const float e = __expf(v[i] - mx);
    v[i] = e;
    sum += e;
  }
  sum = wred_sum(sum);
  if ((t & 63) == 0) red[4 + (t >> 6)] = sum;
  __syncthreads();
  sum = red[4] + red[5] + red[6] + red[7];

  const float rs = qm[r] / sum;
  bf16x8 o;
#pragma unroll
  for (int i = 0; i < 8; i++) o[i] = f2bf(v[i] * rs);
  *(bf16x8*)(P + (long)r * LKK + t * 8) = o;
}

// ---------------------------------------------------------------------------
// Fused residual + LayerNorm: Y = LN(X + R)*w + b  (rows of EMBD)
// MODE bit0: X bf16 (else f32); bit1: R bf16; bit2: Y bf16 (else f32).
// In-place (Y==X) safe: per-thread same-address read-then-write.
// ---------------------------------------------------------------------------
template<int MODE>
__global__ __launch_bounds__(256)
void ln_kernel(const void* __restrict__ Xv, const void* __restrict__ Rv,
               const float* __restrict__ w, const float* __restrict__ bp,
               void* __restrict__ Yv)
{
  __shared__ float red[8];
  const long r = blockIdx.x;
  const int t = threadIdx.x;

  float x0, x1, x2, x3;
  if constexpr (MODE & 1) {
    const bf16x4 xv = ((const bf16x4*)((const bf16_t*)Xv + r * EMBD))[t];
    x0 = (float)xv[0]; x1 = (float)xv[1]; x2 = (float)xv[2]; x3 = (float)xv[3];
  } else {
    const float4 xv = ((const float4*)((const float*)Xv + r * EMBD))[t];
    x0 = xv.x; x1 = xv.y; x2 = xv.z; x3 = xv.w;
  }
  float r0, r1, r2, r3;
  if constexpr (MODE & 2) {
    const bf16x4 rv = ((const bf16x4*)((const bf16_t*)Rv + r * EMBD))[t];
    r0 = (float)rv[0]; r1 = (float)rv[1]; r2 = (float)rv[2]; r3 = (float)rv[3];
  } else {
    const float4 rv = ((const float4*)((const float*)Rv + r * EMBD))[t];
    r0 = rv.x; r1 = rv.y; r2 = rv.z; r3 = rv.w;
  }
  const float s0 = x0 + r0, s1 = x1 + r1, s2 = x2 + r2, s3 = x3 + r3;

  float sum = wred_sum(s0 + s1 + s2 + s3);
  if ((t & 63) == 0) red[t >> 6] = sum;
  __syncthreads();
  const float mu = (red[0] + red[1] + red[2] + red[3]) * (1.0f / EMBD);

  const float d0 = s0 - mu, d1 = s1 - mu, d2 = s2 - mu, d3 = s3 - mu;
  float sq = wred_sum(d0 * d0 + d1 * d1 + d2 * d2 + d3 * d3);
  if ((t & 63) == 0) red[4 + (t >> 6)] = sq;
  __syncthreads();
  const float var = (red[4] + red[5] + red[6] + red[7]) * (1.0f / EMBD);
  const float rstd = rsqrtf(var + 1e-5f);

  const float4 wv = ((const float4*)w)[t];
  const float4 bv = ((const float4*)bp)[t];
  const float y0 = d0 * rstd * wv.x + bv.x;
  const float y1 = d1 * rstd * wv.y + bv.y;
  const float y2 = d2 * rstd * wv.z + bv.z;
  const float y3 = d3 * rstd * wv.w + bv.w;

  if constexpr (MODE & 4) {
    bf16x4 o; o[0] = f2bf(y0); o[1] = f2bf(y1); o[2] = f2bf(y2); o[3] = f2bf(y3);
    ((bf16x4*)((bf16_t*)Yv + r * EMBD))[t] = o;
  } else {
    ((float4*)((float*)Yv + r * EMBD))[t] = make_float4(y0, y1, y2, y3);
  }
}

// flat f32 -> bf16 (vectorized, grid-stride)
__global__ void cvt_kernel(const float* __restrict__ in, bf16_t* __restrict__ out, long n4)
{
  long i = (long)blockIdx.x * 256 + threadIdx.x;
  const long stride = (long)gridDim.x * 256;
  for (; i < n4; i += stride) {
    const float4 v = ((const float4*)in)[i];
    bf16x4 o; o[0] = f2bf(v.x); o[1] = f2bf(v.y); o[2] = f2bf(v.z); o[3] = f2bf(v.w);
    ((bf16x4*)out)[i] = o;
  }
}

// batched [z][rows][cols] f32 -> [z][cols][rows] bf16 (tiled transpose via LDS)
__global__ __launch_bounds__(256)
void transpose_cvt(const float* __restrict__ in, bf16_t* __restrict__ out,
                   int rows, int cols)
{
  __shared__ bf16_t tile[32][33];
  const long zb = (long)blockIdx.z * rows * cols;
  const int cb = blockIdx.x * 32;      // col coord
  const int rb = blockIdx.y * 32;      // row coord
  const int tx = threadIdx.x & 31;
  const int ty = threadIdx.x >> 5;     // 0..7
#pragma unroll
  for (int i = 0; i < 4; i++) {
    const int rr = ty + i * 8;
    tile[rr][tx] = f2bf(in[zb + (long)(rb + rr) * cols + cb + tx]);
  }
  __syncthreads();
#pragma unroll
  for (int i = 0; i < 4; i++) {
    const int cc = ty + i * 8;
    out[zb + (long)(cb + cc) * rows + rb + tx] = tile[tx][cc];
  }
}

// ---------------------------------------------------------------------------
extern "C" void kernel_launch(void* const* d_in, const int* in_sizes, int n_in,
                              void* d_out, int out_size, void* d_ws, size_t ws_size,
                              hipStream_t stream)
{
  const float* q    = (const float*)d_in[0];
  const float* k    = (const float*)d_in[1];
  const float* qm   = (const float*)d_in[2];
  const float* km   = (const float*)d_in[3];
  const float* lnw  = (const float*)d_in[4];
  const float* lnb  = (const float*)d_in[5];
  const float* ln2w = (const float*)d_in[6];
  const float* ln2b = (const float*)d_in[7];
  const float* W1   = (const float*)d_in[8];
  const float* b1   = (const float*)d_in[9];
  const float* W2   = (const float*)d_in[10];
  const float* b2   = (const float*)d_in[11];

  char* ws = (char*)d_ws;
  char* ob = (char*)d_out;
  const float scale = 0.03125f;             // 1/(sqrt(1024)+1e-8)
  const long MB = 1L << 20;
  const long QE = (long)LQ * EMBD;          // 2M elems per batch (Q-shaped)
  const long SS = (long)LQ * LKK;           // 4M elems per batch (S-shaped)

  if (ws_size >= 100 * MB) {
    // ================= Tier A: fully batched (z=8) =================
    // ws:  [0,32) Qb -> attn   [32,64) Kb -> h   [64,96) Kt   [96,100) W1b,W2b
    // out: [0,64) S/P bf16 (in-place softmax) -> y f32
    bf16_t* Qb   = (bf16_t*)ws;
    bf16_t* attn = (bf16_t*)ws;                  // overlays Qb (dead after QK)
    bf16_t* Kb   = (bf16_t*)(ws + 32 * MB);
    bf16_t* h    = (bf16_t*)(ws + 32 * MB);      // overlays Kb (dead after QK)
    bf16_t* Kt   = (bf16_t*)(ws + 64 * MB);
    bf16_t* W1b  = (bf16_t*)(ws + 96 * MB);
    bf16_t* W2b  = (bf16_t*)(ws + 98 * MB);
    bf16_t* Sb   = (bf16_t*)ob;                  // 64 MiB, whole d_out
    float*  y    = (float*)ob;

    cvt_kernel<<<1024, 256, 0, stream>>>(W1, W1b, (long)EMBD * EMBD / 4);
    cvt_kernel<<<1024, 256, 0, stream>>>(W2, W2b, (long)EMBD * EMBD / 4);
    cvt_kernel<<<4096, 256, 0, stream>>>(q, Qb, (long)NB * QE / 4);
    cvt_kernel<<<4096, 256, 0, stream>>>(k, Kb, (long)NB * QE / 4);
    transpose_cvt<<<dim3(EMBD / 32, LKK / 32, NB), 256, 0, stream>>>(k, Kt, LKK, EMBD);

    // S = (Q K^T)/32
    gemm_nt<0><<<dim3(LQ / 256, LKK / 256, NB), 512, 0, stream>>>(
        Qb, Kb, nullptr, Sb, nullptr, scale, LQ, LKK, EMBD, QE, QE, SS);
    // P = qmask * softmax(mask(S))   (in-place)
    softmax_kernel<<<NB * LQ, 256, 0, stream>>>(Sb, Sb, km, qm);
    // attn = P @ K
    gemm_nt<1><<<dim3(LQ / 256, EMBD / 256, NB), 512, 0, stream>>>(
        Sb, Kt, nullptr, attn, nullptr, 0.0f, LQ, EMBD, LKK, SS, (long)EMBD * LKK, QE);
    // x = LN(attn + q) in-place
    ln_kernel<5><<<NB * LQ, 256, 0, stream>>>(attn, q, lnw, lnb, attn);
    // FFN single-shot over 16384 rows
    gemm_nt<2><<<dim3(NB * LQ / 256, EMBD / 256, 1), 512, 0, stream>>>(
        attn, W1b, nullptr, h, b1, 0.0f, NB * LQ, EMBD, EMBD, 0, 0, 0);
    gemm_nt<3><<<dim3(NB * LQ / 256, EMBD / 256, 1), 512, 0, stream>>>(
        h, W2b, y, nullptr, b2, 0.0f, NB * LQ, EMBD, EMBD, 0, 0, 0);
    // out = LN(y + x) in-place
    ln_kernel<2><<<NB * LQ, 256, 0, stream>>>(y, attn, ln2w, ln2b, y);

  } else if (ws_size >= 52 * MB) {
    // ================= Tier B: two half-batches (z=4) =================
    bf16_t* attn = (bf16_t*)ws;
    bf16_t* W1b  = (bf16_t*)(ws + 32 * MB);
    bf16_t* W2b  = (bf16_t*)(ws + 34 * MB);
    bf16_t* Kth  = (bf16_t*)(ws + 36 * MB);
    bf16_t* h    = (bf16_t*)(ws + 36 * MB);      // overlays Kth (dead after PV)
    bf16_t* Sb   = (bf16_t*)ob;
    bf16_t* Qbh  = (bf16_t*)(ob + 32 * MB);
    bf16_t* Kbh  = (bf16_t*)(ob + 48 * MB);
    float*  y    = (float*)ob;

    cvt_kernel<<<1024, 256, 0, stream>>>(W1, W1b, (long)EMBD * EMBD / 4);
    cvt_kernel<<<1024, 256, 0, stream>>>(W2, W2b, (long)EMBD * EMBD / 4);

    for (int it = 0; it < 2; it++) {
      const int bo = it * 4;
      const float* qh = q + bo * QE;
      const float* kh = k + bo * QE;
      cvt_kernel<<<2048, 256, 0, stream>>>(qh, Qbh, 4 * QE / 4);
      cvt_kernel<<<2048, 256, 0, stream>>>(kh, Kbh, 4 * QE / 4);
      transpose_cvt<<<dim3(EMBD / 32, LKK / 32, 4), 256, 0, stream>>>(kh, Kth, LKK, EMBD);

      gemm_nt<0><<<dim3(LQ / 256, LKK / 256, 4), 512, 0, stream>>>(
          Qbh, Kbh, nullptr, Sb, nullptr, scale, LQ, LKK, EMBD, QE, QE, SS);
      softmax_kernel<<<4 * LQ, 256, 0, stream>>>(Sb, Sb, km + bo * LKK, qm + bo * LQ);
      gemm_nt<1><<<dim3(LQ / 256, EMBD / 256, 4), 512, 0, stream>>>(
          Sb, Kth, nullptr, attn + bo * QE, nullptr, 0.0f, LQ, EMBD, LKK,
          SS, (long)EMBD * LKK, QE);
    }
    ln_kernel<5><<<NB * LQ, 256, 0, stream>>>(attn, q, lnw, lnb, attn);
    for (int c = 0; c < 2; c++) {
      bf16_t* xc = attn + (long)c * 8192 * EMBD;
      float*  yc = y + (long)c * 8192 * EMBD;
      gemm_nt<2><<<dim3(8192 / 256, EMBD / 256, 1), 512, 0, stream>>>(
          xc, W1b, nullptr, h, b1, 0.0f, 8192, EMBD, EMBD, 0, 0, 0);
      gemm_nt<3><<<dim3(8192 / 256, EMBD / 256, 1), 512, 0, stream>>>(
          h, W2b, yc, nullptr, b2, 0.0f, 8192, EMBD, EMBD, 0, 0, 0);
    }
    ln_kernel<2><<<NB * LQ, 256, 0, stream>>>(y, attn, ln2w, ln2b, y);

  } else {
    // ================= Tier C: per-batch 44 MiB fallback =================
    if (ws_size < 44 * MB) return;
    bf16_t* attn = (bf16_t*)ws;
    bf16_t* W1b  = (bf16_t*)(ws + 32 * MB);
    bf16_t* W2b  = (bf16_t*)(ws + 34 * MB);
    bf16_t* h    = (bf16_t*)(ws + 36 * MB);
    bf16_t* Sb   = (bf16_t*)(ob);
    bf16_t* Pb   = (bf16_t*)(ob + 8 * MB);
    bf16_t* Qbb  = (bf16_t*)(ob + 16 * MB);
    bf16_t* Kbb  = (bf16_t*)(ob + 20 * MB);
    bf16_t* Ktb  = (bf16_t*)(ob + 24 * MB);

    cvt_kernel<<<1024, 256, 0, stream>>>(W1, W1b, (long)EMBD * EMBD / 4);
    cvt_kernel<<<1024, 256, 0, stream>>>(W2, W2b, (long)EMBD * EMBD / 4);

    for (int b = 0; b < NB; b++) {
      const float* qb = q + b * QE;
      const float* kb = k + b * QE;
      cvt_kernel<<<2048, 256, 0, stream>>>(qb, Qbb, QE / 4);
      cvt_kernel<<<2048, 256, 0, stream>>>(kb, Kbb, QE / 4);
      transpose_cvt<<<dim3(EMBD / 32, LKK / 32, 1), 256, 0, stream>>>(kb, Ktb, LKK, EMBD);

      gemm_nt<0><<<dim3(LQ / 256, LKK / 256, 1), 512, 0, stream>>>(
          Qbb, Kbb, nullptr, Sb, nullptr, scale, LQ, LKK, EMBD, 0, 0, 0);
      softmax_kernel<<<LQ, 256, 0, stream>>>(Sb, Pb, km + (long)b * LKK, qm + (long)b * LQ);
      gemm_nt<1><<<dim3(LQ / 256, EMBD / 256, 1), 512, 0, stream>>>(
          Pb, Ktb, nullptr, attn + b * QE, nullptr, 0.0f, LQ, EMBD, LKK, 0, 0, 0);
    }
    ln_kernel<5><<<NB * LQ, 256, 0, stream>>>(attn, q, lnw, lnb, attn);
    for (int c = 0; c < 4; c++) {
      bf16_t* xc = attn + (long)c * 4096 * EMBD;
      float*  yc = (float*)d_out + (long)c * 4096 * EMBD;
      gemm_nt<2><<<dim3(4096 / 256, EMBD / 256, 1), 512, 0, stream>>>(
          xc, W1b, nullptr, h, b1, 0.0f, 4096, EMBD, EMBD, 0, 0, 0);
      gemm_nt<3><<<dim3(4096 / 256, EMBD / 256, 1), 512, 0, stream>>>(
          h, W2b, yc, nullptr, b2, 0.0f, 4096, EMBD, EMBD, 0, 0, 0);
      ln_kernel<2><<<4096, 256, 0, stream>>>(yc, xc, ln2w, ln2b, yc);
    }
  }
}

// Round 7
// 588.563 us; speedup vs baseline: 1.0487x; 1.0055x over previous
//
#include <hip/hip_runtime.h>
#include <hip/hip_bf16.h>
#include <stdint.h>

// Problem constants (fixed by setup_inputs)
#define NB    8
#define LQ    2048
#define LKK   2048
#define EMBD  1024

typedef __bf16 bf16_t;
typedef __bf16 bf16x8 __attribute__((ext_vector_type(8)));
typedef __bf16 bf16x4 __attribute__((ext_vector_type(4)));
typedef float  f32x4  __attribute__((ext_vector_type(4)));

// RNE float->bf16, branch-free (inputs are finite)
__device__ __forceinline__ bf16_t f2bf(float x) {
  union { float f; uint32_t u; } v; v.f = x;
  uint32_t r = v.u + 0x7fffu + ((v.u >> 16) & 1u);
  uint16_t h = (uint16_t)(r >> 16);
  return __builtin_bit_cast(bf16_t, h);
}

__device__ __forceinline__ float wred_sum(float v) {
#pragma unroll
  for (int o = 32; o; o >>= 1) v += __shfl_xor(v, o);
  return v;
}
__device__ __forceinline__ float wred_max(float v) {
#pragma unroll
  for (int o = 32; o; o >>= 1) v = fmaxf(v, __shfl_xor(v, o));
  return v;
}

// XCD-aware bijective chunk swizzle over flattened grid (requires total%8==0)
__device__ __forceinline__ int xcd_swizzle(int f, int total) {
  if ((total & 7) == 0) { const int cpx = total >> 3; f = (f & 7) * cpx + (f >> 3); }
  return f;
}

// ---------------------------------------------------------------------------
// Batched NT GEMM, 256x256 tile (QK): C[z] = A[z] @ B[z]^T  (bf16 in, f32 acc)
// R4-proven structure: BK=64, 8 waves as 2Mx4N (wave: 128x64 out), dbuf LDS
// (128 KiB), 2-phase pipeline, ONE plain __syncthreads per K-tile, no inline
// asm (compiler schedules the interleave -- measured best, R4=136us vs
// R5/R6 pinned-schedule 168-174us). + XCD swizzle (FETCH 147->49 MB).
// LDS K-slice-major [buf][slice8][row256][8 bf16]: linear in gload_lds slot
// order (rule #21) and conflict-free on ds_read_b128 (0 measured).
// EPI: 0 = bf16 store with scale; 1 = bf16 plain; 2 = +bias ReLU bf16;
//      3 = +bias f32.
// ---------------------------------------------------------------------------
template<int EPI>
__global__ __launch_bounds__(512, 2)
void gemm_nt(const bf16_t* __restrict__ A, const bf16_t* __restrict__ B,
             float* __restrict__ Cf, bf16_t* __restrict__ Cb,
             const float* __restrict__ bias, float scale,
             int M, int N, int K, long sA, long sB, long sC)
{
  __shared__ __align__(16) bf16_t Al[2][8][256][8];
  __shared__ __align__(16) bf16_t Bl[2][8][256][8];

  const int tid  = threadIdx.x;
  const int lane = tid & 63;
  const int wave = tid >> 6;          // 0..7

  const int nbx = gridDim.x, nby = gridDim.y;
  const int f = xcd_swizzle(((int)blockIdx.z * nby + (int)blockIdx.y) * nbx + (int)blockIdx.x,
                            nbx * nby * gridDim.z);
  const int bxi = f % nbx;
  const int byi = (f / nbx) % nby;
  const int bz  = f / (nbx * nby);

  const bf16_t* Ab = A + (long)bz * sA;
  const bf16_t* Bb = B + (long)bz * sB;

  const int bm = bxi * 256;
  const int bn = byi * 256;
  const int wm = (wave >> 2) * 128;   // 2 M-halves
  const int wn = (wave & 3) * 64;     // 4 N-quarters

  f32x4 acc[8][4] = {};

  // staging: thread t, issue i -> LDS slot s = tid + i*512 (16B each);
  // slot -> slice = s>>8, row = s&255.
  const int srow = tid & 255;
  const int sslc = tid >> 8;          // 0 or 1

  // fragment read coords: lane l -> row (l&15), k-slice (l>>4)
  const int fr = lane & 15;
  const int fs = lane >> 4;

  auto STAGE = [&](int bufi, int kt) {
#pragma unroll
    for (int i = 0; i < 4; i++) {
      const int slc = sslc + 2 * i;
      __builtin_amdgcn_global_load_lds(
        (const __attribute__((address_space(1))) void*)(Ab + (long)(bm + srow) * K + kt + slc * 8),
        (__attribute__((address_space(3))) void*)((char*)&Al[bufi][0][0][0] + (tid + i * 512) * 16),
        16, 0, 0);
    }
#pragma unroll
    for (int i = 0; i < 4; i++) {
      const int slc = sslc + 2 * i;
      __builtin_amdgcn_global_load_lds(
        (const __attribute__((address_space(1))) void*)(Bb + (long)(bn + srow) * K + kt + slc * 8),
        (__attribute__((address_space(3))) void*)((char*)&Bl[bufi][0][0][0] + (tid + i * 512) * 16),
        16, 0, 0);
    }
  };

  auto COMPUTE = [&](int bufi) {
#pragma unroll
    for (int kk = 0; kk < 2; kk++) {      // two 32-K steps per 64-K tile
      bf16x8 af[8], bfg[4];
#pragma unroll
      for (int m = 0; m < 8; m++)
        af[m] = *(const bf16x8*)&Al[bufi][4 * kk + fs][wm + m * 16 + fr][0];
#pragma unroll
      for (int n = 0; n < 4; n++)
        bfg[n] = *(const bf16x8*)&Bl[bufi][4 * kk + fs][wn + n * 16 + fr][0];
#pragma unroll
      for (int m = 0; m < 8; m++)
#pragma unroll
        for (int n = 0; n < 4; n++)
          acc[m][n] = __builtin_amdgcn_mfma_f32_16x16x32_bf16(af[m], bfg[n], acc[m][n], 0, 0, 0);
    }
  };

  STAGE(0, 0);
  __syncthreads();
  int buf = 0;
  for (int kt = 64; kt < K; kt += 64) {
    STAGE(buf ^ 1, kt);      // issue next-tile loads first
    COMPUTE(buf);
    __syncthreads();         // single drain per K-tile
    buf ^= 1;
  }
  COMPUTE(buf);

  // C/D layout (m89-verified): col = lane&15, row = (lane>>4)*4 + j
  const int r0 = bm + wm + ((lane >> 4) << 2);
  const int c0 = bn + wn + fr;
  const long cb = (long)bz * sC;
#pragma unroll
  for (int n = 0; n < 4; n++) {
    const int col = c0 + n * 16;
    float bv = 0.0f;
    if constexpr (EPI >= 2) bv = bias[col];
#pragma unroll
    for (int m = 0; m < 8; m++) {
#pragma unroll
      for (int j = 0; j < 4; j++) {
        const int row = r0 + m * 16 + j;
        const long idx = cb + (long)row * N + col;
        float v = acc[m][n][j];
        if constexpr (EPI == 0)      { Cb[idx] = f2bf(v * scale); }
        else if constexpr (EPI == 1) { Cb[idx] = f2bf(v); }
        else if constexpr (EPI == 2) { v += bv; Cb[idx] = f2bf(fmaxf(v, 0.0f)); }
        else                         { v += bv; Cf[idx] = v; }
      }
    }
  }
}

// ---------------------------------------------------------------------------
// Batched NT GEMM, 128x128 tile (PV/FFN): same math, 4 waves as 2x2 (wave:
// 64x64 out), BK=32, dbuf LDS 32 KiB -> ~3 blocks/CU co-resident (m114
// implicit overlap regime; m103's 912 TF structure). 2-phase, plain barrier.
// ---------------------------------------------------------------------------
template<int EPI>
__global__ __launch_bounds__(256, 3)
void gemm_sm(const bf16_t* __restrict__ A, const bf16_t* __restrict__ B,
             float* __restrict__ Cf, bf16_t* __restrict__ Cb,
             const float* __restrict__ bias, float scale,
             int M, int N, int K, long sA, long sB, long sC)
{
  __shared__ __align__(16) bf16_t Al[2][4][128][8];   // 8 KiB per buf
  __shared__ __align__(16) bf16_t Bl[2][4][128][8];

  const int tid  = threadIdx.x;
  const int lane = tid & 63;
  const int wave = tid >> 6;          // 0..3

  const int nbx = gridDim.x, nby = gridDim.y;
  const int f = xcd_swizzle(((int)blockIdx.z * nby + (int)blockIdx.y) * nbx + (int)blockIdx.x,
                            nbx * nby * gridDim.z);
  const int bxi = f % nbx;
  const int byi = (f / nbx) % nby;
  const int bz  = f / (nbx * nby);

  const bf16_t* Ab = A + (long)bz * sA;
  const bf16_t* Bb = B + (long)bz * sB;

  const int bm = bxi * 128;
  const int bn = byi * 128;
  const int wm = (wave >> 1) * 64;
  const int wn = (wave & 1) * 64;

  f32x4 acc[4][4] = {};

  // staging: thread t, issue i -> slot s = tid + i*256; slice = s>>7, row = s&127
  const int srow = tid & 127;
  const int sslc = tid >> 7;          // 0 or 1

  const int fr = lane & 15;
  const int fs = lane >> 4;

  auto STAGE = [&](int bufi, int kt) {
#pragma unroll
    for (int i = 0; i < 2; i++) {
      const int slc = sslc + 2 * i;
      __builtin_amdgcn_global_load_lds(
        (const __attribute__((address_space(1))) void*)(Ab + (long)(bm + srow) * K + kt + slc * 8),
        (__attribute__((address_space(3))) void*)((char*)&Al[bufi][0][0][0] + (tid + i * 256) * 16),
        16, 0, 0);
      __builtin_amdgcn_global_load_lds(
        (const __attribute__((address_space(1))) void*)(Bb + (long)(bn + srow) * K + kt + slc * 8),
        (__attribute__((address_space(3))) void*)((char*)&Bl[bufi][0][0][0] + (tid + i * 256) * 16),
        16, 0, 0);
    }
  };

  auto COMPUTE = [&](int bufi) {
    bf16x8 af[4], bfg[4];
#pragma unroll
    for (int m = 0; m < 4; m++)
      af[m] = *(const bf16x8*)&Al[bufi][fs][wm + m * 16 + fr][0];
#pragma unroll
    for (int n = 0; n < 4; n++)
      bfg[n] = *(const bf16x8*)&Bl[bufi][fs][wn + n * 16 + fr][0];
#pragma unroll
    for (int m = 0; m < 4; m++)
#pragma unroll
      for (int n = 0; n < 4; n++)
        acc[m][n] = __builtin_amdgcn_mfma_f32_16x16x32_bf16(af[m], bfg[n], acc[m][n], 0, 0, 0);
  };

  STAGE(0, 0);
  __syncthreads();
  int buf = 0;
  for (int kt = 32; kt < K; kt += 32) {
    STAGE(buf ^ 1, kt);
    COMPUTE(buf);
    __syncthreads();
    buf ^= 1;
  }
  COMPUTE(buf);

  const int r0 = bm + wm + ((lane >> 4) << 2);
  const int c0 = bn + wn + fr;
  const long cb = (long)bz * sC;
#pragma unroll
  for (int n = 0; n < 4; n++) {
    const int col = c0 + n * 16;
    float bv = 0.0f;
    if constexpr (EPI >= 2) bv = bias[col];
#pragma unroll
    for (int m = 0; m < 4; m++) {
#pragma unroll
      for (int j = 0; j < 4; j++) {
        const int row = r0 + m * 16 + j;
        const long idx = cb + (long)row * N + col;
        float v = acc[m][n][j];
        if constexpr (EPI == 0)      { Cb[idx] = f2bf(v * scale); }
        else if constexpr (EPI == 1) { Cb[idx] = f2bf(v); }
        else if constexpr (EPI == 2) { v += bv; Cb[idx] = f2bf(fmaxf(v, 0.0f)); }
        else                         { v += bv; Cf[idx] = v; }
      }
    }
  }
}

// ---------------------------------------------------------------------------
// Row softmax over S [(nb)*LQ][LKK] bf16 (already scaled) -> P bf16, in-place
// capable (P may == S). km/qm pointers pre-offset to the batch range.
// ---------------------------------------------------------------------------
__global__ __launch_bounds__(256)
void softmax_kernel(const bf16_t* __restrict__ S, bf16_t* __restrict__ P,
                    const float* __restrict__ km, const float* __restrict__ qm)
{
  __shared__ float red[8];
  const int r = blockIdx.x;
  const int b = r >> 11;              // local batch index (r / LQ)
  const int t = threadIdx.x;
  const bf16_t* row = S + (long)r * LKK;

  const bf16x8 sv = *(const bf16x8*)(row + t * 8);
  const float4 k0 = ((const float4*)(km + (long)b * LKK))[2 * t];
  const float4 k1 = ((const float4*)(km + (long)b * LKK))[2 * t + 1];
  const float kmv[8] = {k0.x, k0.y, k0.z, k0.w, k1.x, k1.y, k1.z, k1.w};

  float v[8];
  float mx = -3.4e38f;
#pragma unroll
  for (int i = 0; i < 8; i++) {
    float s = (float)sv[i];
    s = (kmv[i] == 0.0f) ? -4294967295.0f : s;   // NEG_INF
    v[i] = s;
    mx = fmaxf(mx, s);
  }
  mx = wred_max(mx);
  if ((t & 63) == 0) red[t >> 6] = mx;
  __syncthreads();
  mx = fmaxf(fmaxf(red[0], red[1]), fmaxf(red[2], red[3]));

  float sum = 0.0f;
#pragma unroll
  for (int i = 0; i < 8; i++) {
    const float e = __expf(v[i] - mx);
    v[i] = e;
    sum += e;
  }
  sum = wred_sum(sum);
  if ((t & 63) == 0) red[4 + (t >> 6)] = sum;
  __syncthreads();
  sum = red[4] + red[5] + red[6] + red[7];

  const float rs = qm[r] / sum;
  bf16x8 o;
#pragma unroll
  for (int i = 0; i < 8; i++) o[i] = f2bf(v[i] * rs);
  *(bf16x8*)(P + (long)r * LKK + t * 8) = o;
}

// ---------------------------------------------------------------------------
// Fused residual + LayerNorm: Y = LN(X + R)*w + b  (rows of EMBD)
// MODE bit0: X bf16 (else f32); bit1: R bf16; bit2: Y bf16 (else f32).
// In-place (Y==X) safe: per-thread same-address read-then-write.
// ---------------------------------------------------------------------------
template<int MODE>
__global__ __launch_bounds__(256)
void ln_kernel(const void* __restrict__ Xv, const void* __restrict__ Rv,
               const float* __restrict__ w, const float* __restrict__ bp,
               void* __restrict__ Yv)
{
  __shared__ float red[8];
  const long r = blockIdx.x;
  const int t = threadIdx.x;

  float x0, x1, x2, x3;
  if constexpr (MODE & 1) {
    const bf16x4 xv = ((const bf16x4*)((const bf16_t*)Xv + r * EMBD))[t];
    x0 = (float)xv[0]; x1 = (float)xv[1]; x2 = (float)xv[2]; x3 = (float)xv[3];
  } else {
    const float4 xv = ((const float4*)((const float*)Xv + r * EMBD))[t];
    x0 = xv.x; x1 = xv.y; x2 = xv.z; x3 = xv.w;
  }
  float r0, r1, r2, r3;
  if constexpr (MODE & 2) {
    const bf16x4 rv = ((const bf16x4*)((const bf16_t*)Rv + r * EMBD))[t];
    r0 = (float)rv[0]; r1 = (float)rv[1]; r2 = (float)rv[2]; r3 = (float)rv[3];
  } else {
    const float4 rv = ((const float4*)((const float*)Rv + r * EMBD))[t];
    r0 = rv.x; r1 = rv.y; r2 = rv.z; r3 = rv.w;
  }
  const float s0 = x0 + r0, s1 = x1 + r1, s2 = x2 + r2, s3 = x3 + r3;

  float sum = wred_sum(s0 + s1 + s2 + s3);
  if ((t & 63) == 0) red[t >> 6] = sum;
  __syncthreads();
  const float mu = (red[0] + red[1] + red[2] + red[3]) * (1.0f / EMBD);

  const float d0 = s0 - mu, d1 = s1 - mu, d2 = s2 - mu, d3 = s3 - mu;
  float sq = wred_sum(d0 * d0 + d1 * d1 + d2 * d2 + d3 * d3);
  if ((t & 63) == 0) red[4 + (t >> 6)] = sq;
  __syncthreads();
  const float var = (red[4] + red[5] + red[6] + red[7]) * (1.0f / EMBD);
  const float rstd = rsqrtf(var + 1e-5f);

  const float4 wv = ((const float4*)w)[t];
  const float4 bv = ((const float4*)bp)[t];
  const float y0 = d0 * rstd * wv.x + bv.x;
  const float y1 = d1 * rstd * wv.y + bv.y;
  const float y2 = d2 * rstd * wv.z + bv.z;
  const float y3 = d3 * rstd * wv.w + bv.w;

  if constexpr (MODE & 4) {
    bf16x4 o; o[0] = f2bf(y0); o[1] = f2bf(y1); o[2] = f2bf(y2); o[3] = f2bf(y3);
    ((bf16x4*)((bf16_t*)Yv + r * EMBD))[t] = o;
  } else {
    ((float4*)((float*)Yv + r * EMBD))[t] = make_float4(y0, y1, y2, y3);
  }
}

// flat f32 -> bf16 (vectorized, grid-stride)
__global__ void cvt_kernel(const float* __restrict__ in, bf16_t* __restrict__ out, long n4)
{
  long i = (long)blockIdx.x * 256 + threadIdx.x;
  const long stride = (long)gridDim.x * 256;
  for (; i < n4; i += stride) {
    const float4 v = ((const float4*)in)[i];
    bf16x4 o; o[0] = f2bf(v.x); o[1] = f2bf(v.y); o[2] = f2bf(v.z); o[3] = f2bf(v.w);
    ((bf16x4*)out)[i] = o;
  }
}

// batched [z][rows][cols] f32 -> transposed bf16 [z][cols][rows] AND straight
// bf16 copy [z][rows][cols] in one read pass (saves a full re-read of k).
__global__ __launch_bounds__(256)
void transpose_cvt(const float* __restrict__ in, bf16_t* __restrict__ outT,
                   bf16_t* __restrict__ outS, int rows, int cols)
{
  __shared__ bf16_t tile[32][33];
  const long zb = (long)blockIdx.z * rows * cols;
  const int cb = blockIdx.x * 32;      // col coord
  const int rb = blockIdx.y * 32;      // row coord
  const int tx = threadIdx.x & 31;
  const int ty = threadIdx.x >> 5;     // 0..7
#pragma unroll
  for (int i = 0; i < 4; i++) {
    const int rr = ty + i * 8;
    const bf16_t v = f2bf(in[zb + (long)(rb + rr) * cols + cb + tx]);
    tile[rr][tx] = v;
    if (outS != nullptr) outS[zb + (long)(rb + rr) * cols + cb + tx] = v;
  }
  __syncthreads();
#pragma unroll
  for (int i = 0; i < 4; i++) {
    const int cc = ty + i * 8;
    outT[zb + (long)(cb + cc) * rows + rb + tx] = tile[tx][cc];
  }
}

// ---------------------------------------------------------------------------
extern "C" void kernel_launch(void* const* d_in, const int* in_sizes, int n_in,
                              void* d_out, int out_size, void* d_ws, size_t ws_size,
                              hipStream_t stream)
{
  const float* q    = (const float*)d_in[0];
  const float* k    = (const float*)d_in[1];
  const float* qm   = (const float*)d_in[2];
  const float* km   = (const float*)d_in[3];
  const float* lnw  = (const float*)d_in[4];
  const float* lnb  = (const float*)d_in[5];
  const float* ln2w = (const float*)d_in[6];
  const float* ln2b = (const float*)d_in[7];
  const float* W1   = (const float*)d_in[8];
  const float* b1   = (const float*)d_in[9];
  const float* W2   = (const float*)d_in[10];
  const float* b2   = (const float*)d_in[11];

  char* ws = (char*)d_ws;
  char* ob = (char*)d_out;
  const float scale = 0.03125f;             // 1/(sqrt(1024)+1e-8)
  const long MB = 1L << 20;
  const long QE = (long)LQ * EMBD;          // 2M elems per batch (Q-shaped)
  const long SS = (long)LQ * LKK;           // 4M elems per batch (S-shaped)

  if (ws_size >= 100 * MB) {
    // ================= Tier A: fully batched (z=8) =================
    // ws:  [0,32) Qb -> attn   [32,64) Kb -> h   [64,96) Kt   [96,100) W1b,W2b
    // out: [0,64) S/P bf16 (in-place softmax) -> y f32
    bf16_t* Qb   = (bf16_t*)ws;
    bf16_t* attn = (bf16_t*)ws;                  // overlays Qb (dead after QK)
    bf16_t* Kb   = (bf16_t*)(ws + 32 * MB);
    bf16_t* h    = (bf16_t*)(ws + 32 * MB);      // overlays Kb (dead after QK)
    bf16_t* Kt   = (bf16_t*)(ws + 64 * MB);
    bf16_t* W1b  = (bf16_t*)(ws + 96 * MB);
    bf16_t* W2b  = (bf16_t*)(ws + 98 * MB);
    bf16_t* Sb   = (bf16_t*)ob;                  // 64 MiB, whole d_out
    float*  y    = (float*)ob;

    cvt_kernel<<<1024, 256, 0, stream>>>(W1, W1b, (long)EMBD * EMBD / 4);
    cvt_kernel<<<1024, 256, 0, stream>>>(W2, W2b, (long)EMBD * EMBD / 4);
    cvt_kernel<<<4096, 256, 0, stream>>>(q, Qb, (long)NB * QE / 4);
    transpose_cvt<<<dim3(EMBD / 32, LKK / 32, NB), 256, 0, stream>>>(k, Kt, Kb, LKK, EMBD);

    // S = (Q K^T)/32
    gemm_nt<0><<<dim3(LQ / 256, LKK / 256, NB), 512, 0, stream>>>(
        Qb, Kb, nullptr, Sb, nullptr, scale, LQ, LKK, EMBD, QE, QE, SS);
    // P = qmask * softmax(mask(S))   (in-place)
    softmax_kernel<<<NB * LQ, 256, 0, stream>>>(Sb, Sb, km, qm);
    // attn = P @ K
    gemm_sm<1><<<dim3(LQ / 128, EMBD / 128, NB), 256, 0, stream>>>(
        Sb, Kt, nullptr, attn, nullptr, 0.0f, LQ, EMBD, LKK, SS, (long)EMBD * LKK, QE);
    // x = LN(attn + q) in-place
    ln_kernel<5><<<NB * LQ, 256, 0, stream>>>(attn, q, lnw, lnb, attn);
    // FFN single-shot over 16384 rows
    gemm_sm<2><<<dim3(NB * LQ / 128, EMBD / 128, 1), 256, 0, stream>>>(
        attn, W1b, nullptr, h, b1, 0.0f, NB * LQ, EMBD, EMBD, 0, 0, 0);
    gemm_sm<3><<<dim3(NB * LQ / 128, EMBD / 128, 1), 256, 0, stream>>>(
        h, W2b, y, nullptr, b2, 0.0f, NB * LQ, EMBD, EMBD, 0, 0, 0);
    // out = LN(y + x) in-place
    ln_kernel<2><<<NB * LQ, 256, 0, stream>>>(y, attn, ln2w, ln2b, y);

  } else if (ws_size >= 52 * MB) {
    // ================= Tier B: two half-batches (z=4) =================
    bf16_t* attn = (bf16_t*)ws;
    bf16_t* W1b  = (bf16_t*)(ws + 32 * MB);
    bf16_t* W2b  = (bf16_t*)(ws + 34 * MB);
    bf16_t* Kth  = (bf16_t*)(ws + 36 * MB);
    bf16_t* h    = (bf16_t*)(ws + 36 * MB);      // overlays Kth (dead after PV)
    bf16_t* Sb   = (bf16_t*)ob;
    bf16_t* Qbh  = (bf16_t*)(ob + 32 * MB);
    bf16_t* Kbh  = (bf16_t*)(ob + 48 * MB);
    float*  y    = (float*)ob;

    cvt_kernel<<<1024, 256, 0, stream>>>(W1, W1b, (long)EMBD * EMBD / 4);
    cvt_kernel<<<1024, 256, 0, stream>>>(W2, W2b, (long)EMBD * EMBD / 4);

    for (int it = 0; it < 2; it++) {
      const int bo = it * 4;
      const float* qh = q + bo * QE;
      const float* kh = k + bo * QE;
      cvt_kernel<<<2048, 256, 0, stream>>>(qh, Qbh, 4 * QE / 4);
      transpose_cvt<<<dim3(EMBD / 32, LKK / 32, 4), 256, 0, stream>>>(kh, Kth, Kbh, LKK, EMBD);

      gemm_nt<0><<<dim3(LQ / 256, LKK / 256, 4), 512, 0, stream>>>(
          Qbh, Kbh, nullptr, Sb, nullptr, scale, LQ, LKK, EMBD, QE, QE, SS);
      softmax_kernel<<<4 * LQ, 256, 0, stream>>>(Sb, Sb, km + bo * LKK, qm + bo * LQ);
      gemm_sm<1><<<dim3(LQ / 128, EMBD / 128, 4), 256, 0, stream>>>(
          Sb, Kth, nullptr, attn + bo * QE, nullptr, 0.0f, LQ, EMBD, LKK,
          SS, (long)EMBD * LKK, QE);
    }
    ln_kernel<5><<<NB * LQ, 256, 0, stream>>>(attn, q, lnw, lnb, attn);
    for (int c = 0; c < 2; c++) {
      bf16_t* xc = attn + (long)c * 8192 * EMBD;
      float*  yc = y + (long)c * 8192 * EMBD;
      gemm_sm<2><<<dim3(8192 / 128, EMBD / 128, 1), 256, 0, stream>>>(
          xc, W1b, nullptr, h, b1, 0.0f, 8192, EMBD, EMBD, 0, 0, 0);
      gemm_sm<3><<<dim3(8192 / 128, EMBD / 128, 1), 256, 0, stream>>>(
          h, W2b, yc, nullptr, b2, 0.0f, 8192, EMBD, EMBD, 0, 0, 0);
    }
    ln_kernel<2><<<NB * LQ, 256, 0, stream>>>(y, attn, ln2w, ln2b, y);

  } else {
    // ================= Tier C: per-batch 44 MiB fallback =================
    if (ws_size < 44 * MB) return;
    bf16_t* attn = (bf16_t*)ws;
    bf16_t* W1b  = (bf16_t*)(ws + 32 * MB);
    bf16_t* W2b  = (bf16_t*)(ws + 34 * MB);
    bf16_t* h    = (bf16_t*)(ws + 36 * MB);
    bf16_t* Sb   = (bf16_t*)(ob);
    bf16_t* Pb   = (bf16_t*)(ob + 8 * MB);
    bf16_t* Qbb  = (bf16_t*)(ob + 16 * MB);
    bf16_t* Kbb  = (bf16_t*)(ob + 20 * MB);
    bf16_t* Ktb  = (bf16_t*)(ob + 24 * MB);

    cvt_kernel<<<1024, 256, 0, stream>>>(W1, W1b, (long)EMBD * EMBD / 4);
    cvt_kernel<<<1024, 256, 0, stream>>>(W2, W2b, (long)EMBD * EMBD / 4);

    for (int b = 0; b < NB; b++) {
      const float* qb = q + b * QE;
      const float* kb = k + b * QE;
      cvt_kernel<<<2048, 256, 0, stream>>>(qb, Qbb, QE / 4);
      transpose_cvt<<<dim3(EMBD / 32, LKK / 32, 1), 256, 0, stream>>>(kb, Ktb, Kbb, LKK, EMBD);

      gemm_nt<0><<<dim3(LQ / 256, LKK / 256, 1), 512, 0, stream>>>(
          Qbb, Kbb, nullptr, Sb, nullptr, scale, LQ, LKK, EMBD, 0, 0, 0);
      softmax_kernel<<<LQ, 256, 0, stream>>>(Sb, Pb, km + (long)b * LKK, qm + (long)b * LQ);
      gemm_sm<1><<<dim3(LQ / 128, EMBD / 128, 1), 256, 0, stream>>>(
          Pb, Ktb, nullptr, attn + b * QE, nullptr, 0.0f, LQ, EMBD, LKK, 0, 0, 0);
    }
    ln_kernel<5><<<NB * LQ, 256, 0, stream>>>(attn, q, lnw, lnb, attn);
    for (int c = 0; c < 4; c++) {
      bf16_t* xc = attn + (long)c * 4096 * EMBD;
      float*  yc = (float*)d_out + (long)c * 4096 * EMBD;
      gemm_sm<2><<<dim3(4096 / 128, EMBD / 128, 1), 256, 0, stream>>>(
          xc, W1b, nullptr, h, b1, 0.0f, 4096, EMBD, EMBD, 0, 0, 0);
      gemm_sm<3><<<dim3(4096 / 128, EMBD / 128, 1), 256, 0, stream>>>(
          h, W2b, yc, nullptr, b2, 0.0f, 4096, EMBD, EMBD, 0, 0, 0);
      ln_kernel<2><<<4096, 256, 0, stream>>>(yc, xc, ln2w, ln2b, yc);
    }
  }
}

// Round 9
// 520.430 us; speedup vs baseline: 1.1859x; 1.1309x over previous
//
#include <hip/hip_runtime.h>
#include <hip/hip_bf16.h>
#include <stdint.h>

// Problem constants (fixed by setup_inputs)
#define NB    8
#define LQ    2048
#define LKK   2048
#define EMBD  1024

typedef __bf16 bf16_t;
typedef __bf16 bf16x8 __attribute__((ext_vector_type(8)));
typedef __bf16 bf16x4 __attribute__((ext_vector_type(4)));
typedef float  f32x4  __attribute__((ext_vector_type(4)));

// RNE float->bf16, branch-free (inputs are finite)
__device__ __forceinline__ bf16_t f2bf(float x) {
  union { float f; uint32_t u; } v; v.f = x;
  uint32_t r = v.u + 0x7fffu + ((v.u >> 16) & 1u);
  uint16_t h = (uint16_t)(r >> 16);
  return __builtin_bit_cast(bf16_t, h);
}

__device__ __forceinline__ float wred_sum(float v) {
#pragma unroll
  for (int o = 32; o; o >>= 1) v += __shfl_xor(v, o);
  return v;
}
__device__ __forceinline__ float wred_max(float v) {
#pragma unroll
  for (int o = 32; o; o >>= 1) v = fmaxf(v, __shfl_xor(v, o));
  return v;
}

// XCD-aware bijective chunk swizzle over flattened grid (requires total%8==0)
__device__ __forceinline__ int xcd_swizzle(int f, int total) {
  if ((total & 7) == 0) { const int cpx = total >> 3; f = (f & 7) * cpx + (f >> 3); }
  return f;
}

// Common epilogue. C/D layout (m89-verified): col = lane&15, row = (lane>>4)*4+j
template<int EPI>
__device__ __forceinline__ void gemm_epilogue(
    f32x4 (&acc)[8][4], float* Cf, bf16_t* Cb, const float* bias, float scale,
    int N, long cb, int bm, int bn, int wm, int wn, int lane)
{
  const int r0 = bm + wm + ((lane >> 4) << 2);
  const int c0 = bn + wn + (lane & 15);
#pragma unroll
  for (int n = 0; n < 4; n++) {
    const int col = c0 + n * 16;
    float bv = 0.0f;
    if constexpr (EPI >= 2) bv = bias[col];
#pragma unroll
    for (int m = 0; m < 8; m++) {
#pragma unroll
      for (int j = 0; j < 4; j++) {
        const int row = r0 + m * 16 + j;
        const long idx = cb + (long)row * N + col;
        float v = acc[m][n][j];
        if constexpr (EPI == 0)      { Cb[idx] = f2bf(v * scale); }
        else if constexpr (EPI == 1) { Cb[idx] = f2bf(v); }
        else if constexpr (EPI == 2) { v += bv; Cb[idx] = f2bf(fmaxf(v, 0.0f)); }
        else                         { v += bv; Cf[idx] = v; }
      }
    }
  }
}

// ---------------------------------------------------------------------------
// Batched NT GEMM, 256x256 tile: C[z] = A[z] @ B[z]^T  (bf16 in, f32 acc)
// R4-proven structure: BK=64, 8 waves as 2Mx4N, dbuf LDS (128 KiB), 2-phase,
// ONE plain __syncthreads per K-tile (compiler-scheduled) + XCD swizzle.
// LDS K-slice-major [buf][slice8][row256][8 bf16]: linear in gload_lds slot
// order (rule #21), conflict-free on ds_read_b128 (0 measured).
// EPI: 0 bf16*scale; 1 bf16; 2 +bias ReLU bf16; 3 +bias f32.
// ---------------------------------------------------------------------------
template<int EPI>
__global__ __launch_bounds__(512, 2)
void gemm_nt(const bf16_t* __restrict__ A, const bf16_t* __restrict__ B,
             float* __restrict__ Cf, bf16_t* __restrict__ Cb,
             const float* __restrict__ bias, float scale,
             int M, int N, int K, long sA, long sB, long sC)
{
  __shared__ __align__(16) bf16_t Al[2][8][256][8];
  __shared__ __align__(16) bf16_t Bl[2][8][256][8];

  const int tid  = threadIdx.x;
  const int lane = tid & 63;
  const int wave = tid >> 6;          // 0..7

  const int nbx = gridDim.x, nby = gridDim.y;
  const int f = xcd_swizzle(((int)blockIdx.z * nby + (int)blockIdx.y) * nbx + (int)blockIdx.x,
                            nbx * nby * gridDim.z);
  const int bxi = f % nbx;
  const int byi = (f / nbx) % nby;
  const int bz  = f / (nbx * nby);

  const bf16_t* Ab = A + (long)bz * sA;
  const bf16_t* Bb = B + (long)bz * sB;

  const int bm = bxi * 256;
  const int bn = byi * 256;
  const int wm = (wave >> 2) * 128;   // 2 M-halves
  const int wn = (wave & 3) * 64;     // 4 N-quarters

  f32x4 acc[8][4] = {};

  const int srow = tid & 255;
  const int sslc = tid >> 8;          // 0 or 1

  const int fr = lane & 15;
  const int fs = lane >> 4;

  auto STAGE = [&](int bufi, int kt) {
#pragma unroll
    for (int i = 0; i < 4; i++) {
      const int slc = sslc + 2 * i;
      __builtin_amdgcn_global_load_lds(
        (const __attribute__((address_space(1))) void*)(Ab + (long)(bm + srow) * K + kt + slc * 8),
        (__attribute__((address_space(3))) void*)((char*)&Al[bufi][0][0][0] + (tid + i * 512) * 16),
        16, 0, 0);
    }
#pragma unroll
    for (int i = 0; i < 4; i++) {
      const int slc = sslc + 2 * i;
      __builtin_amdgcn_global_load_lds(
        (const __attribute__((address_space(1))) void*)(Bb + (long)(bn + srow) * K + kt + slc * 8),
        (__attribute__((address_space(3))) void*)((char*)&Bl[bufi][0][0][0] + (tid + i * 512) * 16),
        16, 0, 0);
    }
  };

  auto COMPUTE = [&](int bufi) {
#pragma unroll
    for (int kk = 0; kk < 2; kk++) {
      bf16x8 af[8], bfg[4];
#pragma unroll
      for (int m = 0; m < 8; m++)
        af[m] = *(const bf16x8*)&Al[bufi][4 * kk + fs][wm + m * 16 + fr][0];
#pragma unroll
      for (int n = 0; n < 4; n++)
        bfg[n] = *(const bf16x8*)&Bl[bufi][4 * kk + fs][wn + n * 16 + fr][0];
#pragma unroll
      for (int m = 0; m < 8; m++)
#pragma unroll
        for (int n = 0; n < 4; n++)
          acc[m][n] = __builtin_amdgcn_mfma_f32_16x16x32_bf16(af[m], bfg[n], acc[m][n], 0, 0, 0);
    }
  };

  STAGE(0, 0);
  __syncthreads();
  int buf = 0;
  for (int kt = 64; kt < K; kt += 64) {
    STAGE(buf ^ 1, kt);
    COMPUTE(buf);
    __syncthreads();
    buf ^= 1;
  }
  COMPUTE(buf);

  gemm_epilogue<EPI>(acc, Cf, Cb, bias, scale, N, (long)bz * sC, bm, bn, wm, wn, lane);
}

// ---------------------------------------------------------------------------
// EXPERIMENT (A/B vs gemm_nt on the same-shape FFN dispatch): 8-phase-style
// counted-vmcnt pipeline, RACE-FIXED from R8. Same geometry (256², BK=64,
// 8 waves 2Mx4N). Per K-tile: 4 phases x 16 MFMA; each phase stages ONE
// 2-load chunk of tile t+1 (c0=A-h0, c1=B-h0, c2=A-h1, c3=B-h1).
//
// GATING (simulated ledger, chunk=2 loads/wave):
//   prologue: stage c0..c3(t0)=8 in flight; vmcnt(4) retires c0,c1; barrier.
//   p1-end:  vmcnt(4) [tail vmcnt(0)] retires c2,c3(t)   -> p2 reads safe
//   p3-end:  vmcnt(4) [tail skip]     retires c0,c1(t+1) -> next p0 safe
// Every gate sits at the END of the phase BEFORE the consuming ds_read and
// BEFORE a barrier (R6's proven-correct discipline). In-flight floats 4-8,
// never 0 mid-loop (T4). NO sched_barrier(0) (m141 trap). ds_reads are plain
// C++ loads so frag->MFMA deps are compiler-tracked (rule #18 n/a).
// ---------------------------------------------------------------------------
template<int EPI>
__global__ __launch_bounds__(512, 1)
void gemm_nt8(const bf16_t* __restrict__ A, const bf16_t* __restrict__ B,
              float* __restrict__ Cf, bf16_t* __restrict__ Cb,
              const float* __restrict__ bias, float scale,
              int M, int N, int K, long sA, long sB, long sC)
{
  __shared__ __align__(16) bf16_t Al[2][8][256][8];
  __shared__ __align__(16) bf16_t Bl[2][8][256][8];

  const int tid  = threadIdx.x;
  const int lane = tid & 63;
  const int wave = tid >> 6;

  const int nbx = gridDim.x, nby = gridDim.y;
  const int f = xcd_swizzle(((int)blockIdx.z * nby + (int)blockIdx.y) * nbx + (int)blockIdx.x,
                            nbx * nby * gridDim.z);
  const int bxi = f % nbx;
  const int byi = (f / nbx) % nby;
  const int bz  = f / (nbx * nby);

  const bf16_t* Ab = A + (long)bz * sA;
  const bf16_t* Bb = B + (long)bz * sB;

  const int bm = bxi * 256;
  const int bn = byi * 256;
  const int wm = (wave >> 2) * 128;
  const int wn = (wave & 3) * 64;

  f32x4 acc[8][4] = {};

  const int fr = lane & 15;
  const int fs = lane >> 4;

  // chunk c: 0 = A slices0-3, 1 = B slices0-3, 2 = A slices4-7, 3 = B slices4-7
  auto STAGE_CHUNK = [&](int bufi, int kt, int c) {
    const bf16_t* src = (c & 1) ? Bb : Ab;
    const int base    = (c & 1) ? bn : bm;
    char* dst = ((c & 1) ? (char*)&Bl[bufi][0][0][0] : (char*)&Al[bufi][0][0][0])
                + (c >> 1) * 16384;
    const int kofs = kt + (c >> 1) * 32;
#pragma unroll
    for (int i = 0; i < 2; i++) {
      const int slot = tid + i * 512;        // 0..1023
      const int slc  = slot >> 8;            // 0..3 within half
      const int row  = slot & 255;
      __builtin_amdgcn_global_load_lds(
        (const __attribute__((address_space(1))) void*)(src + (long)(base + row) * K + kofs + slc * 8),
        (__attribute__((address_space(3))) void*)(dst + slot * 16), 16, 0, 0);
    }
  };

  auto MFMA16 = [&](bf16x8 (&af)[8], bf16x8 bx, bf16x8 by, int n0, int n1) {
    __builtin_amdgcn_s_setprio(1);
#pragma unroll
    for (int m = 0; m < 8; m++)
      acc[m][n0] = __builtin_amdgcn_mfma_f32_16x16x32_bf16(af[m], bx, acc[m][n0], 0, 0, 0);
#pragma unroll
    for (int m = 0; m < 8; m++)
      acc[m][n1] = __builtin_amdgcn_mfma_f32_16x16x32_bf16(af[m], by, acc[m][n1], 0, 0, 0);
    __builtin_amdgcn_s_setprio(0);
  };

  const int nt = K >> 6;

  // prologue: stage tile 0 fully; gate c0,c1 BEFORE the loop's first reads.
  STAGE_CHUNK(0, 0, 0); STAGE_CHUNK(0, 0, 1);
  STAGE_CHUNK(0, 0, 2); STAGE_CHUNK(0, 0, 3);
  asm volatile("s_waitcnt vmcnt(4)" ::: "memory");
  __builtin_amdgcn_s_barrier();

  for (int t = 0; t < nt; ++t) {
    const int cur = t & 1, nxt = cur ^ 1;
    const bool pf = (t + 1 < nt);
    const int ktn = (t + 1) << 6;
    bf16x8 af[8], b0, b1;

    // ---- phase 0: kk=0, n{0,1}; stage c0(t+1). [c0,c1(t) gated at t-1.p3]
#pragma unroll
    for (int m = 0; m < 8; m++) af[m] = *(const bf16x8*)&Al[cur][fs][wm + m * 16 + fr][0];
    b0 = *(const bf16x8*)&Bl[cur][fs][wn + fr][0];
    b1 = *(const bf16x8*)&Bl[cur][fs][wn + 16 + fr][0];
    if (pf) STAGE_CHUNK(nxt, ktn, 0);
    __builtin_amdgcn_s_barrier();
    asm volatile("s_waitcnt lgkmcnt(0)" ::: "memory");
    MFMA16(af, b0, b1, 0, 1);
    __builtin_amdgcn_s_barrier();

    // ---- phase 1: kk=0, n{2,3}; stage c1(t+1); GATE c2,c3(t) at end.
    b0 = *(const bf16x8*)&Bl[cur][fs][wn + 32 + fr][0];
    b1 = *(const bf16x8*)&Bl[cur][fs][wn + 48 + fr][0];
    if (pf) STAGE_CHUNK(nxt, ktn, 1);
    __builtin_amdgcn_s_barrier();
    asm volatile("s_waitcnt lgkmcnt(0)" ::: "memory");
    MFMA16(af, b0, b1, 2, 3);
    if (pf) asm volatile("s_waitcnt vmcnt(4)" ::: "memory");
    else    asm volatile("s_waitcnt vmcnt(0)" ::: "memory");
    __builtin_amdgcn_s_barrier();

    // ---- phase 2: kk=1, n{0,1}; stage c2(t+1). [c2,c3(t) gated above]
#pragma unroll
    for (int m = 0; m < 8; m++) af[m] = *(const bf16x8*)&Al[cur][4 + fs][wm + m * 16 + fr][0];
    b0 = *(const bf16x8*)&Bl[cur][4 + fs][wn + fr][0];
    b1 = *(const bf16x8*)&Bl[cur][4 + fs][wn + 16 + fr][0];
    if (pf) STAGE_CHUNK(nxt, ktn, 2);
    __builtin_amdgcn_s_barrier();
    asm volatile("s_waitcnt lgkmcnt(0)" ::: "memory");
    MFMA16(af, b0, b1, 0, 1);
    __builtin_amdgcn_s_barrier();

    // ---- phase 3: kk=1, n{2,3}; stage c3(t+1); GATE c0,c1(t+1) at end.
    b0 = *(const bf16x8*)&Bl[cur][4 + fs][wn + 32 + fr][0];
    b1 = *(const bf16x8*)&Bl[cur][4 + fs][wn + 48 + fr][0];
    if (pf) STAGE_CHUNK(nxt, ktn, 3);
    __builtin_amdgcn_s_barrier();
    asm volatile("s_waitcnt lgkmcnt(0)" ::: "memory");
    MFMA16(af, b0, b1, 2, 3);
    if (pf) asm volatile("s_waitcnt vmcnt(4)" ::: "memory");
    __builtin_amdgcn_s_barrier();
  }

  gemm_epilogue<EPI>(acc, Cf, Cb, bias, scale, N, (long)bz * sC, bm, bn, wm, wn, lane);
}

// ---------------------------------------------------------------------------
// Row softmax over S [(nb)*LQ][LKK] bf16 (already scaled) -> P bf16, in-place
// capable (P may == S). km/qm pointers pre-offset to the batch range.
// ---------------------------------------------------------------------------
__global__ __launch_bounds__(256)
void softmax_kernel(const bf16_t* __restrict__ S, bf16_t* __restrict__ P,
                    const float* __restrict__ km, const float* __restrict__ qm)
{
  __shared__ float red[8];
  const int r = blockIdx.x;
  const int b = r >> 11;              // local batch index (r / LQ)
  const int t = threadIdx.x;
  const bf16_t* row = S + (long)r * LKK;

  const bf16x8 sv = *(const bf16x8*)(row + t * 8);
  const float4 k0 = ((const float4*)(km + (long)b * LKK))[2 * t];
  const float4 k1 = ((const float4*)(km + (long)b * LKK))[2 * t + 1];
  const float kmv[8] = {k0.x, k0.y, k0.z, k0.w, k1.x, k1.y, k1.z, k1.w};

  float v[8];
  float mx = -3.4e38f;
#pragma unroll
  for (int i = 0; i < 8; i++) {
    float s = (float)sv[i];
    s = (kmv[i] == 0.0f) ? -4294967295.0f : s;   // NEG_INF
    v[i] = s;
    mx = fmaxf(mx, s);
  }
  mx = wred_max(mx);
  if ((t & 63) == 0) red[t >> 6] = mx;
  __syncthreads();
  mx = fmaxf(fmaxf(red[0], red[1]), fmaxf(red[2], red[3]));

  float sum = 0.0f;
#pragma unroll
  for (int i = 0; i < 8; i++) {
    const float e = __expf(v[i] - mx);
    v[i] = e;
    sum += e;
  }
  sum = wred_sum(sum);
  if ((t & 63) == 0) red[4 + (t >> 6)] = sum;
  __syncthreads();
  sum = red[4] + red[5] + red[6] + red[7];

  const float rs = qm[r] / sum;
  bf16x8 o;
#pragma unroll
  for (int i = 0; i < 8; i++) o[i] = f2bf(v[i] * rs);
  *(bf16x8*)(P + (long)r * LKK + t * 8) = o;
}

// ---------------------------------------------------------------------------
// Fused residual + LayerNorm: Y = LN(X + R)*w + b  (rows of EMBD)
// MODE bit0: X bf16 (else f32); bit1: R bf16; bit2: Y bf16 (else f32).
// In-place (Y==X) safe: per-thread same-address read-then-write.
// ---------------------------------------------------------------------------
template<int MODE>
__global__ __launch_bounds__(256)
void ln_kernel(const void* __restrict__ Xv, const void* __restrict__ Rv,
               const float* __restrict__ w, const float* __restrict__ bp,
               void* __restrict__ Yv)
{
  __shared__ float red[8];
  const long r = blockIdx.x;
  const int t = threadIdx.x;

  float x0, x1, x2, x3;
  if constexpr (MODE & 1) {
    const bf16x4 xv = ((const bf16x4*)((const bf16_t*)Xv + r * EMBD))[t];
    x0 = (float)xv[0]; x1 = (float)xv[1]; x2 = (float)xv[2]; x3 = (float)xv[3];
  } else {
    const float4 xv = ((const float4*)((const float*)Xv + r * EMBD))[t];
    x0 = xv.x; x1 = xv.y; x2 = xv.z; x3 = xv.w;
  }
  float r0, r1, r2, r3;
  if constexpr (MODE & 2) {
    const bf16x4 rv = ((const bf16x4*)((const bf16_t*)Rv + r * EMBD))[t];
    r0 = (float)rv[0]; r1 = (float)rv[1]; r2 = (float)rv[2]; r3 = (float)rv[3];
  } else {
    const float4 rv = ((const float4*)((const float*)Rv + r * EMBD))[t];
    r0 = rv.x; r1 = rv.y; r2 = rv.z; r3 = rv.w;
  }
  const float s0 = x0 + r0, s1 = x1 + r1, s2 = x2 + r2, s3 = x3 + r3;

  float sum = wred_sum(s0 + s1 + s2 + s3);
  if ((t & 63) == 0) red[t >> 6] = sum;
  __syncthreads();
  const float mu = (red[0] + red[1] + red[2] + red[3]) * (1.0f / EMBD);

  const float d0 = s0 - mu, d1 = s1 - mu, d2 = s2 - mu, d3 = s3 - mu;
  float sq = wred_sum(d0 * d0 + d1 * d1 + d2 * d2 + d3 * d3);
  if ((t & 63) == 0) red[4 + (t >> 6)] = sq;
  __syncthreads();
  const float var = (red[4] + red[5] + red[6] + red[7]) * (1.0f / EMBD);
  const float rstd = rsqrtf(var + 1e-5f);

  const float4 wv = ((const float4*)w)[t];
  const float4 bv = ((const float4*)bp)[t];
  const float y0 = d0 * rstd * wv.x + bv.x;
  const float y1 = d1 * rstd * wv.y + bv.y;
  const float y2 = d2 * rstd * wv.z + bv.z;
  const float y3 = d3 * rstd * wv.w + bv.w;

  if constexpr (MODE & 4) {
    bf16x4 o; o[0] = f2bf(y0); o[1] = f2bf(y1); o[2] = f2bf(y2); o[3] = f2bf(y3);
    ((bf16x4*)((bf16_t*)Yv + r * EMBD))[t] = o;
  } else {
    ((float4*)((float*)Yv + r * EMBD))[t] = make_float4(y0, y1, y2, y3);
  }
}

// flat f32 -> bf16 (vectorized, grid-stride)
__global__ void cvt_kernel(const float* __restrict__ in, bf16_t* __restrict__ out, long n4)
{
  long i = (long)blockIdx.x * 256 + threadIdx.x;
  const long stride = (long)gridDim.x * 256;
  for (; i < n4; i += stride) {
    const float4 v = ((const float4*)in)[i];
    bf16x4 o; o[0] = f2bf(v.x); o[1] = f2bf(v.y); o[2] = f2bf(v.z); o[3] = f2bf(v.w);
    ((bf16x4*)out)[i] = o;
  }
}

// batched [z][rows][cols] f32 -> transposed bf16 [z][cols][rows] AND straight
// bf16 copy [z][rows][cols] in one read pass (saves a full re-read of k).
__global__ __launch_bounds__(256)
void transpose_cvt(const float* __restrict__ in, bf16_t* __restrict__ outT,
                   bf16_t* __restrict__ outS, int rows, int cols)
{
  __shared__ bf16_t tile[32][33];
  const long zb = (long)blockIdx.z * rows * cols;
  const int cb = blockIdx.x * 32;      // col coord
  const int rb = blockIdx.y * 32;      // row coord
  const int tx = threadIdx.x & 31;
  const int ty = threadIdx.x >> 5;     // 0..7
#pragma unroll
  for (int i = 0; i < 4; i++) {
    const int rr = ty + i * 8;
    const bf16_t v = f2bf(in[zb + (long)(rb + rr) * cols + cb + tx]);
    tile[rr][tx] = v;
    if (outS != nullptr) outS[zb + (long)(rb + rr) * cols + cb + tx] = v;
  }
  __syncthreads();
#pragma unroll
  for (int i = 0; i < 4; i++) {
    const int cc = ty + i * 8;
    outT[zb + (long)(cb + cc) * rows + rb + tx] = tile[tx][cc];
  }
}

// ---------------------------------------------------------------------------
extern "C" void kernel_launch(void* const* d_in, const int* in_sizes, int n_in,
                              void* d_out, int out_size, void* d_ws, size_t ws_size,
                              hipStream_t stream)
{
  const float* q    = (const float*)d_in[0];
  const float* k    = (const float*)d_in[1];
  const float* qm   = (const float*)d_in[2];
  const float* km   = (const float*)d_in[3];
  const float* lnw  = (const float*)d_in[4];
  const float* lnb  = (const float*)d_in[5];
  const float* ln2w = (const float*)d_in[6];
  const float* ln2b = (const float*)d_in[7];
  const float* W1   = (const float*)d_in[8];
  const float* b1   = (const float*)d_in[9];
  const float* W2   = (const float*)d_in[10];
  const float* b2   = (const float*)d_in[11];

  char* ws = (char*)d_ws;
  char* ob = (char*)d_out;
  const float scale = 0.03125f;             // 1/(sqrt(1024)+1e-8)
  const long MB = 1L << 20;
  const long QE = (long)LQ * EMBD;          // 2M elems per batch (Q-shaped)
  const long SS = (long)LQ * LKK;           // 4M elems per batch (S-shaped)

  if (ws_size >= 100 * MB) {
    // ================= Tier A: fully batched (z=8) =================
    bf16_t* Qb   = (bf16_t*)ws;
    bf16_t* attn = (bf16_t*)ws;                  // overlays Qb (dead after QK)
    bf16_t* Kb   = (bf16_t*)(ws + 32 * MB);
    bf16_t* h    = (bf16_t*)(ws + 32 * MB);      // overlays Kb (dead after QK)
    bf16_t* Kt   = (bf16_t*)(ws + 64 * MB);
    bf16_t* W1b  = (bf16_t*)(ws + 96 * MB);
    bf16_t* W2b  = (bf16_t*)(ws + 98 * MB);
    bf16_t* Sb   = (bf16_t*)ob;                  // 64 MiB, whole d_out
    float*  y    = (float*)ob;

    cvt_kernel<<<1024, 256, 0, stream>>>(W1, W1b, (long)EMBD * EMBD / 4);
    cvt_kernel<<<1024, 256, 0, stream>>>(W2, W2b, (long)EMBD * EMBD / 4);
    cvt_kernel<<<4096, 256, 0, stream>>>(q, Qb, (long)NB * QE / 4);
    transpose_cvt<<<dim3(EMBD / 32, LKK / 32, NB), 256, 0, stream>>>(k, Kt, Kb, LKK, EMBD);

    // S = (Q K^T)/32   [2-phase + swizzle]
    gemm_nt<0><<<dim3(LQ / 256, LKK / 256, NB), 512, 0, stream>>>(
        Qb, Kb, nullptr, Sb, nullptr, scale, LQ, LKK, EMBD, QE, QE, SS);
    // P = qmask * softmax(mask(S))   (in-place)
    softmax_kernel<<<NB * LQ, 256, 0, stream>>>(Sb, Sb, km, qm);
    // attn = P @ K    [2-phase 256² + swizzle]
    gemm_nt<1><<<dim3(LQ / 256, EMBD / 256, NB), 512, 0, stream>>>(
        Sb, Kt, nullptr, attn, nullptr, 0.0f, LQ, EMBD, LKK, SS, (long)EMBD * LKK, QE);
    // x = LN(attn + q) in-place
    ln_kernel<5><<<NB * LQ, 256, 0, stream>>>(attn, q, lnw, lnb, attn);
    // FFN1: EXPERIMENT -- race-fixed 8-phase (A/B vs FFN2's 2-phase, same shape)
    gemm_nt8<2><<<dim3(NB * LQ / 256, EMBD / 256, 1), 512, 0, stream>>>(
        attn, W1b, nullptr, h, b1, 0.0f, NB * LQ, EMBD, EMBD, 0, 0, 0);
    // FFN2: CONTROL -- 2-phase
    gemm_nt<3><<<dim3(NB * LQ / 256, EMBD / 256, 1), 512, 0, stream>>>(
        h, W2b, y, nullptr, b2, 0.0f, NB * LQ, EMBD, EMBD, 0, 0, 0);
    // out = LN(y + x) in-place
    ln_kernel<2><<<NB * LQ, 256, 0, stream>>>(y, attn, ln2w, ln2b, y);

  } else if (ws_size >= 52 * MB) {
    // ================= Tier B: two half-batches (z=4) =================
    bf16_t* attn = (bf16_t*)ws;
    bf16_t* W1b  = (bf16_t*)(ws + 32 * MB);
    bf16_t* W2b  = (bf16_t*)(ws + 34 * MB);
    bf16_t* Kth  = (bf16_t*)(ws + 36 * MB);
    bf16_t* h    = (bf16_t*)(ws + 36 * MB);      // overlays Kth (dead after PV)
    bf16_t* Sb   = (bf16_t*)ob;
    bf16_t* Qbh  = (bf16_t*)(ob + 32 * MB);
    bf16_t* Kbh  = (bf16_t*)(ob + 48 * MB);
    float*  y    = (float*)ob;

    cvt_kernel<<<1024, 256, 0, stream>>>(W1, W1b, (long)EMBD * EMBD / 4);
    cvt_kernel<<<1024, 256, 0, stream>>>(W2, W2b, (long)EMBD * EMBD / 4);

    for (int it = 0; it < 2; it++) {
      const int bo = it * 4;
      const float* qh = q + bo * QE;
      const float* kh = k + bo * QE;
      cvt_kernel<<<2048, 256, 0, stream>>>(qh, Qbh, 4 * QE / 4);
      transpose_cvt<<<dim3(EMBD / 32, LKK / 32, 4), 256, 0, stream>>>(kh, Kth, Kbh, LKK, EMBD);

      gemm_nt<0><<<dim3(LQ / 256, LKK / 256, 4), 512, 0, stream>>>(
          Qbh, Kbh, nullptr, Sb, nullptr, scale, LQ, LKK, EMBD, QE, QE, SS);
      softmax_kernel<<<4 * LQ, 256, 0, stream>>>(Sb, Sb, km + bo * LKK, qm + bo * LQ);
      gemm_nt<1><<<dim3(LQ / 256, EMBD / 256, 4), 512, 0, stream>>>(
          Sb, Kth, nullptr, attn + bo * QE, nullptr, 0.0f, LQ, EMBD, LKK,
          SS, (long)EMBD * LKK, QE);
    }
    ln_kernel<5><<<NB * LQ, 256, 0, stream>>>(attn, q, lnw, lnb, attn);
    for (int c = 0; c < 2; c++) {
      bf16_t* xc = attn + (long)c * 8192 * EMBD;
      float*  yc = y + (long)c * 8192 * EMBD;
      gemm_nt<2><<<dim3(8192 / 256, EMBD / 256, 1), 512, 0, stream>>>(
          xc, W1b, nullptr, h, b1, 0.0f, 8192, EMBD, EMBD, 0, 0, 0);
      gemm_nt<3><<<dim3(8192 / 256, EMBD / 256, 1), 512, 0, stream>>>(
          h, W2b, yc, nullptr, b2, 0.0f, 8192, EMBD, EMBD, 0, 0, 0);
    }
    ln_kernel<2><<<NB * LQ, 256, 0, stream>>>(y, attn, ln2w, ln2b, y);

  } else {
    // ================= Tier C: per-batch 44 MiB fallback =================
    if (ws_size < 44 * MB) return;
    bf16_t* attn = (bf16_t*)ws;
    bf16_t* W1b  = (bf16_t*)(ws + 32 * MB);
    bf16_t* W2b  = (bf16_t*)(ws + 34 * MB);
    bf16_t* h    = (bf16_t*)(ws + 36 * MB);
    bf16_t* Sb   = (bf16_t*)(ob);
    bf16_t* Pb   = (bf16_t*)(ob + 8 * MB);
    bf16_t* Qbb  = (bf16_t*)(ob + 16 * MB);
    bf16_t* Kbb  = (bf16_t*)(ob + 20 * MB);
    bf16_t* Ktb  = (bf16_t*)(ob + 24 * MB);

    cvt_kernel<<<1024, 256, 0, stream>>>(W1, W1b, (long)EMBD * EMBD / 4);
    cvt_kernel<<<1024, 256, 0, stream>>>(W2, W2b, (long)EMBD * EMBD / 4);

    for (int b = 0; b < NB; b++) {
      const float* qb = q + b * QE;
      const float* kb = k + b * QE;
      cvt_kernel<<<2048, 256, 0, stream>>>(qb, Qbb, QE / 4);
      transpose_cvt<<<dim3(EMBD / 32, LKK / 32, 1), 256, 0, stream>>>(kb, Ktb, Kbb, LKK, EMBD);

      gemm_nt<0><<<dim3(LQ / 256, LKK / 256, 1), 512, 0, stream>>>(
          Qbb, Kbb, nullptr, Sb, nullptr, scale, LQ, LKK, EMBD, 0, 0, 0);
      softmax_kernel<<<LQ, 256, 0, stream>>>(Sb, Pb, km + (long)b * LKK, qm + (long)b * LQ);
      gemm_nt<1><<<dim3(LQ / 256, EMBD / 256, 1), 512, 0, stream>>>(
          Pb, Ktb, nullptr, attn + b * QE, nullptr, 0.0f, LQ, EMBD, LKK, 0, 0, 0);
    }
    ln_kernel<5><<<NB * LQ, 256, 0, stream>>>(attn, q, lnw, lnb, attn);
    for (int c = 0; c < 4; c++) {
      bf16_t* xc = attn + (long)c * 4096 * EMBD;
      float*  yc = (float*)d_out + (long)c * 4096 * EMBD;
      gemm_nt<2><<<dim3(4096 / 256, EMBD / 256, 1), 512, 0, stream>>>(
          xc, W1b, nullptr, h, b1, 0.0f, 4096, EMBD, EMBD, 0, 0, 0);
      gemm_nt<3><<<dim3(4096 / 256, EMBD / 256, 1), 512, 0, stream>>>(
          h, W2b, yc, nullptr, b2, 0.0f, 4096, EMBD, EMBD, 0, 0, 0);
      ln_kernel<2><<<4096, 256, 0, stream>>>(yc, xc, ln2w, ln2b, yc);
    }
  }
}

// Round 10
// 456.045 us; speedup vs baseline: 1.3534x; 1.1412x over previous
//
#include <hip/hip_runtime.h>
#include <hip/hip_bf16.h>
#include <stdint.h>

// Problem constants (fixed by setup_inputs)
#define NB    8
#define LQ    2048
#define LKK   2048
#define EMBD  1024

typedef __bf16 bf16_t;
typedef __bf16 bf16x8 __attribute__((ext_vector_type(8)));
typedef __bf16 bf16x4 __attribute__((ext_vector_type(4)));
typedef float  f32x4  __attribute__((ext_vector_type(4)));

// RNE float->bf16, branch-free (inputs are finite)
__device__ __forceinline__ bf16_t f2bf(float x) {
  union { float f; uint32_t u; } v; v.f = x;
  uint32_t r = v.u + 0x7fffu + ((v.u >> 16) & 1u);
  uint16_t h = (uint16_t)(r >> 16);
  return __builtin_bit_cast(bf16_t, h);
}

__device__ __forceinline__ float wred_sum(float v) {
#pragma unroll
  for (int o = 32; o; o >>= 1) v += __shfl_xor(v, o);
  return v;
}
__device__ __forceinline__ float wred_max(float v) {
#pragma unroll
  for (int o = 32; o; o >>= 1) v = fmaxf(v, __shfl_xor(v, o));
  return v;
}

// ---------------------------------------------------------------------------
// Batched NT GEMM, 256x256 tile: C[z] = A[z] @ B[z]^T  (bf16 in, f32 acc)
// Main loop: R4-proven 2-phase (BK=64, 8 waves 2Mx4N, dbuf LDS, one plain
// __syncthreads per K-tile, compiler-scheduled). NO XCD swizzle (measured
// -9% in our L3-resident regime, R4 vs R9).
// NEW epilogue: wave n-cols remapped to nc = n*64 + (wave&3)*16 (64
// contiguous cols per n) + LDS-bounce through a 128 KiB f32 slab (reuses
// staging LDS; bit4-XOR on (row>>2)&1 keeps bank aliasing at free 2-way).
// C-write becomes 16x bf16x8 / 32x f32x4 per thread at 256 B segments,
// replacing 128 scalar stores at 32-64 B segments.
// LDS K-slice-major [buf][slice8][row256][8 bf16]: linear in gload_lds slot
// order (rule #21), conflict-free on ds_read_b128 (0 measured).
// EPI: 0 bf16*scale; 1 bf16; 2 +bias ReLU bf16; 3 +bias f32.
// ---------------------------------------------------------------------------
template<int EPI>
__global__ __launch_bounds__(512, 1)
void gemm_nt(const bf16_t* __restrict__ A, const bf16_t* __restrict__ B,
             float* __restrict__ Cf, bf16_t* __restrict__ Cb,
             const float* __restrict__ bias, float scale,
             int M, int N, int K, long sA, long sB, long sC)
{
  __shared__ __align__(16) char smem[131072];
  typedef bf16_t ldsbuf_t[8][256][8];            // 32 KiB per buffer
  ldsbuf_t* Abuf = (ldsbuf_t*)smem;              // Abuf[0..1]
  ldsbuf_t* Bbuf = (ldsbuf_t*)(smem + 65536);    // Bbuf[0..1]

  const int tid  = threadIdx.x;
  const int lane = tid & 63;
  const int wave = tid >> 6;          // 0..7
  const int wq   = wave & 3;          // n-quarter selector
  const int bz   = blockIdx.z;

  const bf16_t* Ab = A + (long)bz * sA;
  const bf16_t* Bb = B + (long)bz * sB;

  const int bm = blockIdx.x * 256;
  const int bn = blockIdx.y * 256;
  const int wm = (wave >> 2) * 128;   // 2 M-halves

  f32x4 acc[8][4] = {};

  const int srow = tid & 255;
  const int sslc = tid >> 8;          // 0 or 1

  const int fr = lane & 15;
  const int fs = lane >> 4;

  auto STAGE = [&](int bufi, int kt) {
#pragma unroll
    for (int i = 0; i < 4; i++) {
      const int slc = sslc + 2 * i;
      __builtin_amdgcn_global_load_lds(
        (const __attribute__((address_space(1))) void*)(Ab + (long)(bm + srow) * K + kt + slc * 8),
        (__attribute__((address_space(3))) void*)((char*)&Abuf[bufi][0][0][0] + (tid + i * 512) * 16),
        16, 0, 0);
    }
#pragma unroll
    for (int i = 0; i < 4; i++) {
      const int slc = sslc + 2 * i;
      __builtin_amdgcn_global_load_lds(
        (const __attribute__((address_space(1))) void*)(Bb + (long)(bn + srow) * K + kt + slc * 8),
        (__attribute__((address_space(3))) void*)((char*)&Bbuf[bufi][0][0][0] + (tid + i * 512) * 16),
        16, 0, 0);
    }
  };

  auto COMPUTE = [&](int bufi) {
#pragma unroll
    for (int kk = 0; kk < 2; kk++) {
      bf16x8 af[8], bfg[4];
#pragma unroll
      for (int m = 0; m < 8; m++)
        af[m] = *(const bf16x8*)&Abuf[bufi][4 * kk + fs][wm + m * 16 + fr][0];
#pragma unroll
      for (int n = 0; n < 4; n++)
        bfg[n] = *(const bf16x8*)&Bbuf[bufi][4 * kk + fs][n * 64 + wq * 16 + fr][0];
#pragma unroll
      for (int m = 0; m < 8; m++)
#pragma unroll
        for (int n = 0; n < 4; n++)
          acc[m][n] = __builtin_amdgcn_mfma_f32_16x16x32_bf16(af[m], bfg[n], acc[m][n], 0, 0, 0);
    }
  };

  STAGE(0, 0);
  __syncthreads();
  int buf = 0;
  for (int kt = 64; kt < K; kt += 64) {
    STAGE(buf ^ 1, kt);
    COMPUTE(buf);
    __syncthreads();
    buf ^= 1;
  }
  COMPUTE(buf);

  // ---- epilogue: LDS-bounced, coalesced C-write ----
  // acc[m][n][j] holds C[bm + wm + m*16 + (lane>>4)*4 + j]
  //                    [bn + n*64 + wq*16 + (lane&15)]
  float* slab = (float*)smem;                    // 256 x 128 f32 = 128 KiB
  const long cbase = (long)bz * sC;
#pragma unroll
  for (int h = 0; h < 2; h++) {                  // col-halves of 128
    __syncthreads();                             // LDS free (readers done)
#pragma unroll
    for (int nn = 0; nn < 2; nn++) {
      const int n = 2 * h + nn;
      const int colb = nn * 64 + wq * 16 + fr;   // 0..127 within half
#pragma unroll
      for (int m = 0; m < 8; m++) {
        const int rbase = wm + m * 16 + ((lane >> 4) << 2);
#pragma unroll
        for (int j = 0; j < 4; j++) {
          const int row = rbase + j;
          slab[row * 128 + (colb ^ (((row >> 2) & 1) << 4))] = acc[m][n][j];
        }
      }
    }
    __syncthreads();
    const int hcol = bn + h * 128;
    if constexpr (EPI == 3) {
      // f32 out: 16 passes x (16 rows x 32 thr x f32x4), 256 B segments
#pragma unroll
      for (int p = 0; p < 16; p++) {
        const int row = p * 16 + (tid >> 5);
        const int c4  = (tid & 31) * 4;
        f32x4 v = *(const f32x4*)&slab[row * 128 + (c4 ^ (((row >> 2) & 1) << 4))];
        const float4 bv = *(const float4*)&bias[hcol + c4];
        v[0] += bv.x; v[1] += bv.y; v[2] += bv.z; v[3] += bv.w;
        *(f32x4*)&Cf[cbase + (long)(bm + row) * N + hcol + c4] = v;
      }
    } else {
      // bf16 out: 8 passes x (32 rows x 16 thr x bf16x8), 256 B segments
#pragma unroll
      for (int p = 0; p < 8; p++) {
        const int row  = p * 32 + (tid >> 4);
        const int c8   = (tid & 15) * 8;
        const int flip = ((row >> 2) & 1) << 4;
        const f32x4 v0 = *(const f32x4*)&slab[row * 128 + (c8 ^ flip)];
        const f32x4 v1 = *(const f32x4*)&slab[row * 128 + ((c8 + 4) ^ flip)];
        const float vv[8] = {v0[0], v0[1], v0[2], v0[3], v1[0], v1[1], v1[2], v1[3]};
        bf16x8 o;
        if constexpr (EPI == 0) {
#pragma unroll
          for (int e = 0; e < 8; e++) o[e] = f2bf(vv[e] * scale);
        } else if constexpr (EPI == 1) {
#pragma unroll
          for (int e = 0; e < 8; e++) o[e] = f2bf(vv[e]);
        } else {   // EPI == 2: +bias, ReLU
          const float4 b0 = *(const float4*)&bias[hcol + c8];
          const float4 b1 = *(const float4*)&bias[hcol + c8 + 4];
          const float bb[8] = {b0.x, b0.y, b0.z, b0.w, b1.x, b1.y, b1.z, b1.w};
#pragma unroll
          for (int e = 0; e < 8; e++) o[e] = f2bf(fmaxf(vv[e] + bb[e], 0.0f));
        }
        *(bf16x8*)&Cb[cbase + (long)(bm + row) * N + hcol + c8] = o;
      }
    }
  }
}

// ---------------------------------------------------------------------------
// Row softmax over S [(nb)*LQ][LKK] bf16 (already scaled) -> P bf16, in-place
// capable (P may == S). km/qm pointers pre-offset to the batch range.
// ---------------------------------------------------------------------------
__global__ __launch_bounds__(256)
void softmax_kernel(const bf16_t* __restrict__ S, bf16_t* __restrict__ P,
                    const float* __restrict__ km, const float* __restrict__ qm)
{
  __shared__ float red[8];
  const int r = blockIdx.x;
  const int b = r >> 11;              // local batch index (r / LQ)
  const int t = threadIdx.x;
  const bf16_t* row = S + (long)r * LKK;

  const bf16x8 sv = *(const bf16x8*)(row + t * 8);
  const float4 k0 = ((const float4*)(km + (long)b * LKK))[2 * t];
  const float4 k1 = ((const float4*)(km + (long)b * LKK))[2 * t + 1];
  const float kmv[8] = {k0.x, k0.y, k0.z, k0.w, k1.x, k1.y, k1.z, k1.w};

  float v[8];
  float mx = -3.4e38f;
#pragma unroll
  for (int i = 0; i < 8; i++) {
    float s = (float)sv[i];
    s = (kmv[i] == 0.0f) ? -4294967295.0f : s;   // NEG_INF
    v[i] = s;
    mx = fmaxf(mx, s);
  }
  mx = wred_max(mx);
  if ((t & 63) == 0) red[t >> 6] = mx;
  __syncthreads();
  mx = fmaxf(fmaxf(red[0], red[1]), fmaxf(red[2], red[3]));

  float sum = 0.0f;
#pragma unroll
  for (int i = 0; i < 8; i++) {
    const float e = __expf(v[i] - mx);
    v[i] = e;
    sum += e;
  }
  sum = wred_sum(sum);
  if ((t & 63) == 0) red[4 + (t >> 6)] = sum;
  __syncthreads();
  sum = red[4] + red[5] + red[6] + red[7];

  const float rs = qm[r] / sum;
  bf16x8 o;
#pragma unroll
  for (int i = 0; i < 8; i++) o[i] = f2bf(v[i] * rs);
  *(bf16x8*)(P + (long)r * LKK + t * 8) = o;
}

// ---------------------------------------------------------------------------
// Fused residual + LayerNorm: Y = LN(X + R)*w + b  (rows of EMBD)
// MODE bit0: X bf16 (else f32); bit1: R bf16; bit2: Y bf16 (else f32).
// In-place (Y==X) safe: per-thread same-address read-then-write.
// ---------------------------------------------------------------------------
template<int MODE>
__global__ __launch_bounds__(256)
void ln_kernel(const void* __restrict__ Xv, const void* __restrict__ Rv,
               const float* __restrict__ w, const float* __restrict__ bp,
               void* __restrict__ Yv)
{
  __shared__ float red[8];
  const long r = blockIdx.x;
  const int t = threadIdx.x;

  float x0, x1, x2, x3;
  if constexpr (MODE & 1) {
    const bf16x4 xv = ((const bf16x4*)((const bf16_t*)Xv + r * EMBD))[t];
    x0 = (float)xv[0]; x1 = (float)xv[1]; x2 = (float)xv[2]; x3 = (float)xv[3];
  } else {
    const float4 xv = ((const float4*)((const float*)Xv + r * EMBD))[t];
    x0 = xv.x; x1 = xv.y; x2 = xv.z; x3 = xv.w;
  }
  float r0, r1, r2, r3;
  if constexpr (MODE & 2) {
    const bf16x4 rv = ((const bf16x4*)((const bf16_t*)Rv + r * EMBD))[t];
    r0 = (float)rv[0]; r1 = (float)rv[1]; r2 = (float)rv[2]; r3 = (float)rv[3];
  } else {
    const float4 rv = ((const float4*)((const float*)Rv + r * EMBD))[t];
    r0 = rv.x; r1 = rv.y; r2 = rv.z; r3 = rv.w;
  }
  const float s0 = x0 + r0, s1 = x1 + r1, s2 = x2 + r2, s3 = x3 + r3;

  float sum = wred_sum(s0 + s1 + s2 + s3);
  if ((t & 63) == 0) red[t >> 6] = sum;
  __syncthreads();
  const float mu = (red[0] + red[1] + red[2] + red[3]) * (1.0f / EMBD);

  const float d0 = s0 - mu, d1 = s1 - mu, d2 = s2 - mu, d3 = s3 - mu;
  float sq = wred_sum(d0 * d0 + d1 * d1 + d2 * d2 + d3 * d3);
  if ((t & 63) == 0) red[4 + (t >> 6)] = sq;
  __syncthreads();
  const float var = (red[4] + red[5] + red[6] + red[7]) * (1.0f / EMBD);
  const float rstd = rsqrtf(var + 1e-5f);

  const float4 wv = ((const float4*)w)[t];
  const float4 bv = ((const float4*)bp)[t];
  const float y0 = d0 * rstd * wv.x + bv.x;
  const float y1 = d1 * rstd * wv.y + bv.y;
  const float y2 = d2 * rstd * wv.z + bv.z;
  const float y3 = d3 * rstd * wv.w + bv.w;

  if constexpr (MODE & 4) {
    bf16x4 o; o[0] = f2bf(y0); o[1] = f2bf(y1); o[2] = f2bf(y2); o[3] = f2bf(y3);
    ((bf16x4*)((bf16_t*)Yv + r * EMBD))[t] = o;
  } else {
    ((float4*)((float*)Yv + r * EMBD))[t] = make_float4(y0, y1, y2, y3);
  }
}

// flat f32 -> bf16 (vectorized, grid-stride)
__global__ void cvt_kernel(const float* __restrict__ in, bf16_t* __restrict__ out, long n4)
{
  long i = (long)blockIdx.x * 256 + threadIdx.x;
  const long stride = (long)gridDim.x * 256;
  for (; i < n4; i += stride) {
    const float4 v = ((const float4*)in)[i];
    bf16x4 o; o[0] = f2bf(v.x); o[1] = f2bf(v.y); o[2] = f2bf(v.z); o[3] = f2bf(v.w);
    ((bf16x4*)out)[i] = o;
  }
}

// batched [z][rows][cols] f32 -> transposed bf16 [z][cols][rows] AND straight
// bf16 copy [z][rows][cols] in one read pass (saves a full re-read of k).
__global__ __launch_bounds__(256)
void transpose_cvt(const float* __restrict__ in, bf16_t* __restrict__ outT,
                   bf16_t* __restrict__ outS, int rows, int cols)
{
  __shared__ bf16_t tile[32][33];
  const long zb = (long)blockIdx.z * rows * cols;
  const int cb = blockIdx.x * 32;      // col coord
  const int rb = blockIdx.y * 32;      // row coord
  const int tx = threadIdx.x & 31;
  const int ty = threadIdx.x >> 5;     // 0..7
#pragma unroll
  for (int i = 0; i < 4; i++) {
    const int rr = ty + i * 8;
    const bf16_t v = f2bf(in[zb + (long)(rb + rr) * cols + cb + tx]);
    tile[rr][tx] = v;
    if (outS != nullptr) outS[zb + (long)(rb + rr) * cols + cb + tx] = v;
  }
  __syncthreads();
#pragma unroll
  for (int i = 0; i < 4; i++) {
    const int cc = ty + i * 8;
    outT[zb + (long)(cb + cc) * rows + rb + tx] = tile[tx][cc];
  }
}

// ---------------------------------------------------------------------------
extern "C" void kernel_launch(void* const* d_in, const int* in_sizes, int n_in,
                              void* d_out, int out_size, void* d_ws, size_t ws_size,
                              hipStream_t stream)
{
  const float* q    = (const float*)d_in[0];
  const float* k    = (const float*)d_in[1];
  const float* qm   = (const float*)d_in[2];
  const float* km   = (const float*)d_in[3];
  const float* lnw  = (const float*)d_in[4];
  const float* lnb  = (const float*)d_in[5];
  const float* ln2w = (const float*)d_in[6];
  const float* ln2b = (const float*)d_in[7];
  const float* W1   = (const float*)d_in[8];
  const float* b1   = (const float*)d_in[9];
  const float* W2   = (const float*)d_in[10];
  const float* b2   = (const float*)d_in[11];

  char* ws = (char*)d_ws;
  char* ob = (char*)d_out;
  const float scale = 0.03125f;             // 1/(sqrt(1024)+1e-8)
  const long MB = 1L << 20;
  const long QE = (long)LQ * EMBD;          // 2M elems per batch (Q-shaped)
  const long SS = (long)LQ * LKK;           // 4M elems per batch (S-shaped)

  if (ws_size >= 100 * MB) {
    // ================= Tier A: fully batched (z=8) =================
    bf16_t* Qb   = (bf16_t*)ws;
    bf16_t* attn = (bf16_t*)ws;                  // overlays Qb (dead after QK)
    bf16_t* Kb   = (bf16_t*)(ws + 32 * MB);
    bf16_t* h    = (bf16_t*)(ws + 32 * MB);      // overlays Kb (dead after QK)
    bf16_t* Kt   = (bf16_t*)(ws + 64 * MB);
    bf16_t* W1b  = (bf16_t*)(ws + 96 * MB);
    bf16_t* W2b  = (bf16_t*)(ws + 98 * MB);
    bf16_t* Sb   = (bf16_t*)ob;                  // 64 MiB, whole d_out
    float*  y    = (float*)ob;

    cvt_kernel<<<1024, 256, 0, stream>>>(W1, W1b, (long)EMBD * EMBD / 4);
    cvt_kernel<<<1024, 256, 0, stream>>>(W2, W2b, (long)EMBD * EMBD / 4);
    cvt_kernel<<<4096, 256, 0, stream>>>(q, Qb, (long)NB * QE / 4);
    transpose_cvt<<<dim3(EMBD / 32, LKK / 32, NB), 256, 0, stream>>>(k, Kt, Kb, LKK, EMBD);

    // S = (Q K^T)/32
    gemm_nt<0><<<dim3(LQ / 256, LKK / 256, NB), 512, 0, stream>>>(
        Qb, Kb, nullptr, Sb, nullptr, scale, LQ, LKK, EMBD, QE, QE, SS);
    // P = qmask * softmax(mask(S))   (in-place)
    softmax_kernel<<<NB * LQ, 256, 0, stream>>>(Sb, Sb, km, qm);
    // attn = P @ K
    gemm_nt<1><<<dim3(LQ / 256, EMBD / 256, NB), 512, 0, stream>>>(
        Sb, Kt, nullptr, attn, nullptr, 0.0f, LQ, EMBD, LKK, SS, (long)EMBD * LKK, QE);
    // x = LN(attn + q) in-place
    ln_kernel<5><<<NB * LQ, 256, 0, stream>>>(attn, q, lnw, lnb, attn);
    // FFN
    gemm_nt<2><<<dim3(NB * LQ / 256, EMBD / 256, 1), 512, 0, stream>>>(
        attn, W1b, nullptr, h, b1, 0.0f, NB * LQ, EMBD, EMBD, 0, 0, 0);
    gemm_nt<3><<<dim3(NB * LQ / 256, EMBD / 256, 1), 512, 0, stream>>>(
        h, W2b, y, nullptr, b2, 0.0f, NB * LQ, EMBD, EMBD, 0, 0, 0);
    // out = LN(y + x) in-place
    ln_kernel<2><<<NB * LQ, 256, 0, stream>>>(y, attn, ln2w, ln2b, y);

  } else if (ws_size >= 52 * MB) {
    // ================= Tier B: two half-batches (z=4) =================
    bf16_t* attn = (bf16_t*)ws;
    bf16_t* W1b  = (bf16_t*)(ws + 32 * MB);
    bf16_t* W2b  = (bf16_t*)(ws + 34 * MB);
    bf16_t* Kth  = (bf16_t*)(ws + 36 * MB);
    bf16_t* h    = (bf16_t*)(ws + 36 * MB);      // overlays Kth (dead after PV)
    bf16_t* Sb   = (bf16_t*)ob;
    bf16_t* Qbh  = (bf16_t*)(ob + 32 * MB);
    bf16_t* Kbh  = (bf16_t*)(ob + 48 * MB);
    float*  y    = (float*)ob;

    cvt_kernel<<<1024, 256, 0, stream>>>(W1, W1b, (long)EMBD * EMBD / 4);
    cvt_kernel<<<1024, 256, 0, stream>>>(W2, W2b, (long)EMBD * EMBD / 4);

    for (int it = 0; it < 2; it++) {
      const int bo = it * 4;
      const float* qh = q + bo * QE;
      const float* kh = k + bo * QE;
      cvt_kernel<<<2048, 256, 0, stream>>>(qh, Qbh, 4 * QE / 4);
      transpose_cvt<<<dim3(EMBD / 32, LKK / 32, 4), 256, 0, stream>>>(kh, Kth, Kbh, LKK, EMBD);

      gemm_nt<0><<<dim3(LQ / 256, LKK / 256, 4), 512, 0, stream>>>(
          Qbh, Kbh, nullptr, Sb, nullptr, scale, LQ, LKK, EMBD, QE, QE, SS);
      softmax_kernel<<<4 * LQ, 256, 0, stream>>>(Sb, Sb, km + bo * LKK, qm + bo * LQ);
      gemm_nt<1><<<dim3(LQ / 256, EMBD / 256, 4), 512, 0, stream>>>(
          Sb, Kth, nullptr, attn + bo * QE, nullptr, 0.0f, LQ, EMBD, LKK,
          SS, (long)EMBD * LKK, QE);
    }
    ln_kernel<5><<<NB * LQ, 256, 0, stream>>>(attn, q, lnw, lnb, attn);
    for (int c = 0; c < 2; c++) {
      bf16_t* xc = attn + (long)c * 8192 * EMBD;
      float*  yc = y + (long)c * 8192 * EMBD;
      gemm_nt<2><<<dim3(8192 / 256, EMBD / 256, 1), 512, 0, stream>>>(
          xc, W1b, nullptr, h, b1, 0.0f, 8192, EMBD, EMBD, 0, 0, 0);
      gemm_nt<3><<<dim3(8192 / 256, EMBD / 256, 1), 512, 0, stream>>>(
          h, W2b, yc, nullptr, b2, 0.0f, 8192, EMBD, EMBD, 0, 0, 0);
    }
    ln_kernel<2><<<NB * LQ, 256, 0, stream>>>(y, attn, ln2w, ln2b, y);

  } else {
    // ================= Tier C: per-batch 44 MiB fallback =================
    if (ws_size < 44 * MB) return;
    bf16_t* attn = (bf16_t*)ws;
    bf16_t* W1b  = (bf16_t*)(ws + 32 * MB);
    bf16_t* W2b  = (bf16_t*)(ws + 34 * MB);
    bf16_t* h    = (bf16_t*)(ws + 36 * MB);
    bf16_t* Sb   = (bf16_t*)(ob);
    bf16_t* Pb   = (bf16_t*)(ob + 8 * MB);
    bf16_t* Qbb  = (bf16_t*)(ob + 16 * MB);
    bf16_t* Kbb  = (bf16_t*)(ob + 20 * MB);
    bf16_t* Ktb  = (bf16_t*)(ob + 24 * MB);

    cvt_kernel<<<1024, 256, 0, stream>>>(W1, W1b, (long)EMBD * EMBD / 4);
    cvt_kernel<<<1024, 256, 0, stream>>>(W2, W2b, (long)EMBD * EMBD / 4);

    for (int b = 0; b < NB; b++) {
      const float* qb = q + b * QE;
      const float* kb = k + b * QE;
      cvt_kernel<<<2048, 256, 0, stream>>>(qb, Qbb, QE / 4);
      transpose_cvt<<<dim3(EMBD / 32, LKK / 32, 1), 256, 0, stream>>>(kb, Ktb, Kbb, LKK, EMBD);

      gemm_nt<0><<<dim3(LQ / 256, LKK / 256, 1), 512, 0, stream>>>(
          Qbb, Kbb, nullptr, Sb, nullptr, scale, LQ, LKK, EMBD, 0, 0, 0);
      softmax_kernel<<<LQ, 256, 0, stream>>>(Sb, Pb, km + (long)b * LKK, qm + (long)b * LQ);
      gemm_nt<1><<<dim3(LQ / 256, EMBD / 256, 1), 512, 0, stream>>>(
          Pb, Ktb, nullptr, attn + b * QE, nullptr, 0.0f, LQ, EMBD, LKK, 0, 0, 0);
    }
    ln_kernel<5><<<NB * LQ, 256, 0, stream>>>(attn, q, lnw, lnb, attn);
    for (int c = 0; c < 4; c++) {
      bf16_t* xc = attn + (long)c * 4096 * EMBD;
      float*  yc = (float*)d_out + (long)c * 4096 * EMBD;
      gemm_nt<2><<<dim3(4096 / 256, EMBD / 256, 1), 512, 0, stream>>>(
          xc, W1b, nullptr, h, b1, 0.0f, 4096, EMBD, EMBD, 0, 0, 0);
      gemm_nt<3><<<dim3(4096 / 256, EMBD / 256, 1), 512, 0, stream>>>(
          h, W2b, yc, nullptr, b2, 0.0f, 4096, EMBD, EMBD, 0, 0, 0);
      ln_kernel<2><<<4096, 256, 0, stream>>>(yc, xc, ln2w, ln2b, yc);
    }
  }
}